// Round 1
// 646.756 us; speedup vs baseline: 1.4982x; 1.4982x over previous
//
#include <hip/hip_runtime.h>
#include <hip/hip_bf16.h>

// Problem constants (fixed by the reference setup)
#define N_VERTS   100000
#define N_HGE     10000
#define N_INC     1600000
#define N_EDGES   1600000
#define C_IN      256
#define C_MID     128
#define C_OUT     64
#define NEG       0.2f

// Radix-partition parameters.
// Buckets sized so one bucket's slots fit in 64KB LDS:
//   E-buckets: 64 hyperedges,  mean 10240 slots (cap 16384)
//   V-buckets: 512 vertices,   mean  8192 slots (cap 16384)
#define EBSHIFT 6
#define NB_E    157              // ceil(10000/64)
#define VBSHIFT 9
#define NB_V    196              // ceil(100000/512)
#define NB_MAX  196
#define PAIRS_PER_BLOCK 4096     // 256 threads x 16
#define QP 16
#define BUCKET_CAP 16384

// ---------------------------------------------------------------------------
// MLP: h = leaky_relu(x @ W1 + b1) @ W2 + b2   (all f32)
// 32 vertices per block, 256 threads = 64 j-lanes x 4 vert-groups (8 verts).
// ---------------------------------------------------------------------------
#define VPB 32
__global__ __launch_bounds__(256) void
mlp_kernel(const float* __restrict__ x, const float* __restrict__ W1,
           const float* __restrict__ b1, const float* __restrict__ W2,
           const float* __restrict__ b2, float* __restrict__ h) {
    __shared__ float xs[VPB][C_IN];    // 32 KB
    __shared__ float mid[VPB][C_MID];  // 16 KB
    const int t  = threadIdx.x;
    const int v0 = blockIdx.x * VPB;
    const int j0 = t & 63;
    const int vbase = (t >> 6) * 8;

    {
        const float* xp = x + (size_t)v0 * C_IN;
#pragma unroll
        for (int it = 0; it < 8; ++it) {
            const int idx = it * 256 + t;       // float4 index
            const int row = idx >> 6;
            const int c4  = (idx & 63) * 4;
            *(float4*)&xs[row][c4] = *(const float4*)&xp[(size_t)row * C_IN + c4];
        }
    }
    __syncthreads();

    {   // layer 1
        float acc0[8], acc1[8];
        const float bA = b1[j0], bB = b1[j0 + 64];
#pragma unroll
        for (int i = 0; i < 8; ++i) { acc0[i] = bA; acc1[i] = bB; }
        for (int k = 0; k < C_IN; k += 4) {
            float4 xv[8];
#pragma unroll
            for (int i = 0; i < 8; ++i)
                xv[i] = *(const float4*)&xs[vbase + i][k];
#pragma unroll
            for (int kk = 0; kk < 4; ++kk) {
                const float w0 = W1[(k + kk) * C_MID + j0];
                const float w1 = W1[(k + kk) * C_MID + j0 + 64];
#pragma unroll
                for (int i = 0; i < 8; ++i) {
                    const float xvv = kk == 0 ? xv[i].x : kk == 1 ? xv[i].y
                                   : kk == 2 ? xv[i].z : xv[i].w;
                    acc0[i] += xvv * w0;
                    acc1[i] += xvv * w1;
                }
            }
        }
#pragma unroll
        for (int i = 0; i < 8; ++i) {
            const float a = acc0[i], b = acc1[i];
            mid[vbase + i][j0]      = a > 0.f ? a : NEG * a;
            mid[vbase + i][j0 + 64] = b > 0.f ? b : NEG * b;
        }
    }
    __syncthreads();

    {   // layer 2
        float acc[8];
        const float bias = b2[j0];
#pragma unroll
        for (int i = 0; i < 8; ++i) acc[i] = bias;
        for (int k = 0; k < C_MID; k += 4) {
            float4 xv[8];
#pragma unroll
            for (int i = 0; i < 8; ++i)
                xv[i] = *(const float4*)&mid[vbase + i][k];
#pragma unroll
            for (int kk = 0; kk < 4; ++kk) {
                const float w0 = W2[(k + kk) * C_OUT + j0];
#pragma unroll
                for (int i = 0; i < 8; ++i) {
                    const float xvv = kk == 0 ? xv[i].x : kk == 1 ? xv[i].y
                                   : kk == 2 ? xv[i].z : xv[i].w;
                    acc[i] += xvv * w0;
                }
            }
        }
#pragma unroll
        for (int i = 0; i < 8; ++i)
            h[(size_t)(v0 + vbase + i) * C_OUT + j0] = acc[i];
    }
}

// ---------------------------------------------------------------------------
// Bucket-granularity count: replaces the 4.8M-global-atomic count_kernel.
// Per-block LDS histogram over <=196 buckets, then ONE global atomic per
// (block, bucket): ~215K global atomics instead of 4.8M scattered RMWs.
// ---------------------------------------------------------------------------
__global__ __launch_bounds__(256) void
bucket_count_kernel(const int* __restrict__ hg_e, const int* __restrict__ hg_v,
                    const int* __restrict__ g_dst,
                    int* __restrict__ bktcnt_e, int* __restrict__ bktcnt_vhg,
                    int* __restrict__ bktcnt_vg) {
    __shared__ int hist[NB_MAX];
    const int t  = threadIdx.x;
    const int i0 = blockIdx.x * PAIRS_PER_BLOCK + t;

    for (int table = 0; table < 3; ++table) {
        const int* dsts; int* bktcnt; int shift, nb;
        if (table == 0)      { dsts = hg_e;  bktcnt = bktcnt_e;   shift = EBSHIFT; nb = NB_E; }
        else if (table == 1) { dsts = hg_v;  bktcnt = bktcnt_vhg; shift = VBSHIFT; nb = NB_V; }
        else                 { dsts = g_dst; bktcnt = bktcnt_vg;  shift = VBSHIFT; nb = NB_V; }

        if (t < nb) hist[t] = 0;
        __syncthreads();
#pragma unroll
        for (int q = 0; q < QP; ++q) {
            const int i = i0 + q * 256;
            if (i < N_INC) atomicAdd(&hist[dsts[i] >> shift], 1);
        }
        __syncthreads();
        if (t < nb) {
            const int c = hist[t];
            if (c) atomicAdd(&bktcnt[t], c);
        }
        __syncthreads();   // hist reused next table
    }
}

// Three tiny exclusive scans over bucket counts (<=196 each) in one dispatch.
__global__ __launch_bounds__(256) void
bucket_scan_kernel(const int* __restrict__ bktcnt_e,   int* __restrict__ bstart_e,
                   const int* __restrict__ bktcnt_vhg, int* __restrict__ bstart_vhg,
                   const int* __restrict__ bktcnt_vg,  int* __restrict__ bstart_vg) {
    __shared__ int s[256];
    const int* cnt; int* bs; int nb;
    if (blockIdx.x == 0)      { cnt = bktcnt_e;   bs = bstart_e;   nb = NB_E; }
    else if (blockIdx.x == 1) { cnt = bktcnt_vhg; bs = bstart_vhg; nb = NB_V; }
    else                      { cnt = bktcnt_vg;  bs = bstart_vg;  nb = NB_V; }
    const int t = threadIdx.x;
    const int own = (t < nb) ? cnt[t] : 0;
    s[t] = own;
    __syncthreads();
    for (int d = 1; d < 256; d <<= 1) {
        int v = (t >= d) ? s[t - d] : 0;
        __syncthreads();
        s[t] += v;
        __syncthreads();
    }
    if (t < nb) bs[t] = s[t] - own;   // exclusive
}

// ---------------------------------------------------------------------------
// Phase A: radix partition. Each block handles 4096 pairs for all 3 tables.
// LDS histogram -> one global atomic per (block,bucket) reserves a dense run
// in the bucket's record region -> append (dst,payload) records.
// Only needs bucket starts now (not per-dst CSR).
// ---------------------------------------------------------------------------
__global__ __launch_bounds__(256) void
partitionA_kernel(const int* __restrict__ hg_v, const int* __restrict__ hg_e,
                  const int* __restrict__ g_src, const int* __restrict__ g_dst,
                  const int* __restrict__ bstart_e, const int* __restrict__ bstart_vhg,
                  const int* __restrict__ bstart_vg,
                  int* __restrict__ bcur_e, int* __restrict__ bcur_vhg,
                  int* __restrict__ bcur_vg,
                  uint2* __restrict__ rec_e, uint2* __restrict__ rec_vhg,
                  uint2* __restrict__ rec_vg) {
    __shared__ int hist[NB_MAX];
    __shared__ int gb[NB_MAX];
    __shared__ int bb[NB_MAX];
    const int t  = threadIdx.x;
    const int i0 = blockIdx.x * PAIRS_PER_BLOCK + t;

    for (int table = 0; table < 3; ++table) {
        const int *dsts, *pays, *bstart;
        int *bcur; uint2* rec;
        int shift, nb;
        if (table == 0)      { dsts = hg_e;  pays = hg_v;  bstart = bstart_e;
                               bcur = bcur_e;   rec = rec_e;   shift = EBSHIFT; nb = NB_E; }
        else if (table == 1) { dsts = hg_v;  pays = hg_e;  bstart = bstart_vhg;
                               bcur = bcur_vhg; rec = rec_vhg; shift = VBSHIFT; nb = NB_V; }
        else                 { dsts = g_dst; pays = g_src; bstart = bstart_vg;
                               bcur = bcur_vg;  rec = rec_vg;  shift = VBSHIFT; nb = NB_V; }

        if (t < nb) hist[t] = 0;
        __syncthreads();

        int d[QP], p[QP], bk[QP], rk[QP];
#pragma unroll
        for (int q = 0; q < QP; ++q) {
            const int i = i0 + q * 256;
            if (i < N_INC) {
                d[q]  = dsts[i];
                p[q]  = pays[i];
                bk[q] = d[q] >> shift;
                rk[q] = atomicAdd(&hist[bk[q]], 1);
            } else bk[q] = -1;
        }
        __syncthreads();

        if (t < nb) {
            gb[t] = atomicAdd(&bcur[t], hist[t]);
            bb[t] = bstart[t];
        }
        __syncthreads();

#pragma unroll
        for (int q = 0; q < QP; ++q) {
            if (bk[q] >= 0) {
                const int pos = bb[bk[q]] + gb[bk[q]] + rk[q];
                rec[pos] = make_uint2((unsigned)d[q], (unsigned)p[q]);
            }
        }
        __syncthreads();   // hist/gb/bb reused next table
    }
}

// ---------------------------------------------------------------------------
// Phase B: one block per bucket. Derives per-dst degrees + CSR offsets itself
// (count in LDS -> 512-wide LDS exclusive scan -> write deg/off coalesced),
// then builds the bucket's slot contents in LDS and streams them out dense.
// ---------------------------------------------------------------------------
#define GRID_B (NB_E + 2 * NB_V)
__global__ __launch_bounds__(256) void
partitionB_kernel(const uint2* __restrict__ rec_e, const uint2* __restrict__ rec_vhg,
                  const uint2* __restrict__ rec_vg,
                  const int* __restrict__ bstart_e, const int* __restrict__ bstart_vhg,
                  const int* __restrict__ bstart_vg,
                  int* __restrict__ deg_e, int* __restrict__ deg_vhg,
                  int* __restrict__ deg_vg,
                  int* __restrict__ off_e, int* __restrict__ off_vhg,
                  int* __restrict__ off_vg,
                  int* __restrict__ slot_e, int* __restrict__ slot_vhg,
                  int* __restrict__ slot_vg) {
    __shared__ int slotbuf[BUCKET_CAP];   // 64 KB
    __shared__ int cnt_l[1 << VBSHIFT];   // 2 KB
    __shared__ int cur_l[1 << VBSHIFT];   // 2 KB
    __shared__ int part[256];             // 1 KB

    int blk = blockIdx.x;
    const uint2* rec; const int* bstart; int* deg; int* off; int* slot;
    int b, shift, ndst, nb;
    if (blk < NB_E) {
        rec = rec_e; bstart = bstart_e; deg = deg_e; off = off_e; slot = slot_e;
        shift = EBSHIFT; ndst = N_HGE; nb = NB_E; b = blk;
    } else if (blk < NB_E + NB_V) {
        rec = rec_vhg; bstart = bstart_vhg; deg = deg_vhg; off = off_vhg; slot = slot_vhg;
        shift = VBSHIFT; ndst = N_VERTS; nb = NB_V; b = blk - NB_E;
    } else {
        rec = rec_vg; bstart = bstart_vg; deg = deg_vg; off = off_vg; slot = slot_vg;
        shift = VBSHIFT; ndst = N_VERTS; nb = NB_V; b = blk - NB_E - NB_V;
    }
    const int t    = threadIdx.x;
    const int dlo  = b << shift;
    const int nd   = 1 << shift;
    const int ndc  = min(nd, ndst - dlo);
    const int bs   = bstart[b];
    const int be   = (b == nb - 1) ? N_INC : bstart[b + 1];
    const int bcnt = be - bs;

    // pass 1: per-dst counts in LDS
    for (int j = t; j < nd; j += 256) cnt_l[j] = 0;
    __syncthreads();
    for (int i = bs + t; i < be; i += 256)
        atomicAdd(&cnt_l[(int)rec[i].x - dlo], 1);
    __syncthreads();

    // exclusive scan over nd (64 or 512) counts with 256 threads
    const int chunk = (nd + 255) / 256;     // 1 or 2
    const int lo = t * chunk;
    const int hi = min(lo + chunk, nd);
    int s = 0;
    for (int j = lo; j < hi; ++j) s += cnt_l[j];
    part[t] = s;
    __syncthreads();
    for (int d = 1; d < 256; d <<= 1) {
        int v = (t >= d) ? part[t - d] : 0;
        __syncthreads();
        part[t] += v;
        __syncthreads();
    }
    int run = (t > 0) ? part[t - 1] : 0;
    for (int j = lo; j < hi; ++j) { cur_l[j] = run; run += cnt_l[j]; }
    __syncthreads();

    // emit CSR (deg + global off) for this bucket's dst range, coalesced
    for (int j = t; j < ndc; j += 256) {
        deg[dlo + j] = cnt_l[j];
        off[dlo + j] = bs + cur_l[j];
    }
    __syncthreads();   // cur_l becomes the scatter cursor below

    // pass 2: scatter payloads (rec re-read hits L2/L3)
    if (bcnt <= BUCKET_CAP) {
        for (int i = bs + t; i < be; i += 256) {
            const uint2 r = rec[i];
            const int lpos = atomicAdd(&cur_l[(int)r.x - dlo], 1);
            slotbuf[lpos] = (int)r.y;
        }
        __syncthreads();
        for (int i = t; i < bcnt; i += 256)
            slot[bs + i] = slotbuf[i];
    } else {
        // statistically unreachable fallback (keeps correctness airtight)
        for (int i = bs + t; i < be; i += 256) {
            const uint2 r = rec[i];
            const int pos = bs + atomicAdd(&cur_l[(int)r.x - dlo], 1);
            slot[pos] = (int)r.y;
        }
    }
}

// ---------------------------------------------------------------------------
// v2e gather: one wave per hyperedge, lane = channel.
// ---------------------------------------------------------------------------
__global__ void gather_e_kernel(const int* __restrict__ slot, const int* __restrict__ off,
                                const int* __restrict__ deg, const float* __restrict__ h,
                                float* __restrict__ e_feat) {
    const int wid  = (blockIdx.x * blockDim.x + threadIdx.x) >> 6;
    const int lane = threadIdx.x & 63;
    if (wid >= N_HGE) return;
    const int n    = deg[wid];
    const int base = off[wid];
    float acc = 0.f;
    int j = 0;
    for (; j + 4 <= n; j += 4) {
        const int v0 = slot[base + j + 0];
        const int v1 = slot[base + j + 1];
        const int v2 = slot[base + j + 2];
        const int v3 = slot[base + j + 3];
        const float r0 = h[(size_t)v0 * C_OUT + lane];
        const float r1 = h[(size_t)v1 * C_OUT + lane];
        const float r2 = h[(size_t)v2 * C_OUT + lane];
        const float r3 = h[(size_t)v3 * C_OUT + lane];
        acc += (r0 + r1) + (r2 + r3);
    }
    for (; j < n; ++j)
        acc += h[(size_t)slot[base + j] * C_OUT + lane];
    e_feat[(size_t)wid * C_OUT + lane] = acc / fmaxf((float)n, 1.f);
}

// ---------------------------------------------------------------------------
// Fused per-vertex: x_hg gather (over e_feat) + x_g gather (over h) +
// softmax-weighted fuse + leaky -> out. One wave per vertex, lane = channel.
// ---------------------------------------------------------------------------
__global__ void vertex_out_kernel(const int* __restrict__ slot_vhg,
                                  const int* __restrict__ off_vhg,
                                  const int* __restrict__ deg_vhg,
                                  const int* __restrict__ slot_vg,
                                  const int* __restrict__ off_vg,
                                  const int* __restrict__ deg_vg,
                                  const float* __restrict__ e_feat,
                                  const float* __restrict__ h,
                                  const float* __restrict__ w,
                                  float* __restrict__ out) {
    const int wid  = (blockIdx.x * blockDim.x + threadIdx.x) >> 6;
    const int lane = threadIdx.x & 63;
    if (wid >= N_VERTS) return;

    float acc_hg = 0.f;
    {
        const int n = deg_vhg[wid];
        const int base = off_vhg[wid];
        int j = 0;
        for (; j + 4 <= n; j += 4) {
            const int e0 = slot_vhg[base + j + 0];
            const int e1 = slot_vhg[base + j + 1];
            const int e2 = slot_vhg[base + j + 2];
            const int e3 = slot_vhg[base + j + 3];
            const float r0 = e_feat[(size_t)e0 * C_OUT + lane];
            const float r1 = e_feat[(size_t)e1 * C_OUT + lane];
            const float r2 = e_feat[(size_t)e2 * C_OUT + lane];
            const float r3 = e_feat[(size_t)e3 * C_OUT + lane];
            acc_hg += (r0 + r1) + (r2 + r3);
        }
        for (; j < n; ++j)
            acc_hg += e_feat[(size_t)slot_vhg[base + j] * C_OUT + lane];
        acc_hg /= fmaxf((float)n, 1.f);
    }

    float acc_g = 0.f;
    {
        const int n = deg_vg[wid];
        const int base = off_vg[wid];
        int j = 0;
        for (; j + 4 <= n; j += 4) {
            const int v0 = slot_vg[base + j + 0];
            const int v1 = slot_vg[base + j + 1];
            const int v2 = slot_vg[base + j + 2];
            const int v3 = slot_vg[base + j + 3];
            const float r0 = h[(size_t)v0 * C_OUT + lane];
            const float r1 = h[(size_t)v1 * C_OUT + lane];
            const float r2 = h[(size_t)v2 * C_OUT + lane];
            const float r3 = h[(size_t)v3 * C_OUT + lane];
            acc_g += (r0 + r1) + (r2 + r3);
        }
        for (; j < n; ++j)
            acc_g += h[(size_t)slot_vg[base + j] * C_OUT + lane];
        acc_g /= fmaxf((float)n, 1.f);
    }

    const float w0 = w[0], w1 = w[1];
    const float m  = fmaxf(w0, w1);
    const float e0 = __expf(w0 - m), e1 = __expf(w1 - m);
    const float sw0 = e0 / (e0 + e1), sw1 = e1 / (e0 + e1);

    const float hv = h[(size_t)wid * C_OUT + lane];
    float o = sw0 * 0.5f * (acc_g + acc_hg) + sw1 * hv;
    o = o > 0.f ? o : NEG * o;
    out[(size_t)wid * C_OUT + lane] = o;
}

// ---------------------------------------------------------------------------
extern "C" void kernel_launch(void* const* d_in, const int* in_sizes, int n_in,
                              void* d_out, int out_size, void* d_ws, size_t ws_size,
                              hipStream_t stream) {
    const float* x    = (const float*)d_in[0];
    const float* W1   = (const float*)d_in[1];
    const float* b1   = (const float*)d_in[2];
    const float* W2   = (const float*)d_in[3];
    const float* b2   = (const float*)d_in[4];
    const float* w    = (const float*)d_in[5];
    const int*  hg_v  = (const int*)d_in[6];
    const int*  hg_e  = (const int*)d_in[7];
    const int*  g_src = (const int*)d_in[8];
    const int*  g_dst = (const int*)d_in[9];
    float* out = (float*)d_out;

    // ---- workspace layout ----
    // Region R (reused): rec arrays during CSR build, then h + e_feat.
    uint2* rec_e   = (uint2*)d_ws;                 // N_INC   (12.8 MB)
    uint2* rec_vhg = rec_e   + N_INC;              // N_INC   (12.8 MB)
    uint2* rec_vg  = rec_vhg + N_INC;              // N_EDGES (12.8 MB)
    float* h       = (float*)d_ws;                 // N_VERTS*64 (25.6 MB) - after B
    float* e_feat  = h + (size_t)N_VERTS * C_OUT;  // N_HGE*64   (2.56 MB) - after B

    int* slot_e    = (int*)(rec_vg + N_EDGES);     // N_INC
    int* slot_vhg  = slot_e   + N_INC;             // N_INC
    int* slot_vg   = slot_vhg + N_INC;             // N_EDGES
    // zeroed int region:
    int* bktcnt_e   = slot_vg  + N_EDGES;          // NB_E
    int* bktcnt_vhg = bktcnt_e   + NB_E;           // NB_V
    int* bktcnt_vg  = bktcnt_vhg + NB_V;           // NB_V
    int* bcur_e     = bktcnt_vg  + NB_V;           // NB_E
    int* bcur_vhg   = bcur_e     + NB_E;           // NB_V
    int* bcur_vg    = bcur_vhg   + NB_V;           // NB_V
    // not zeroed:
    int* bstart_e   = bcur_vg    + NB_V;           // NB_E
    int* bstart_vhg = bstart_e   + NB_E;           // NB_V
    int* bstart_vg  = bstart_vhg + NB_V;           // NB_V
    int* deg_e      = bstart_vg  + NB_V;           // N_HGE
    int* deg_vhg    = deg_e      + N_HGE;          // N_VERTS
    int* deg_vg     = deg_vhg    + N_VERTS;        // N_VERTS
    int* off_e      = deg_vg     + N_VERTS;        // N_HGE
    int* off_vhg    = off_e      + N_HGE;          // N_VERTS
    int* off_vg     = off_vhg    + N_VERTS;        // N_VERTS

    const size_t zero_elems = 2 * ((size_t)NB_E + 2 * (size_t)NB_V);
    hipMemsetAsync(bktcnt_e, 0, zero_elems * sizeof(int), stream);

    // ---- CSR build (bucket-granularity count only; no per-dst atomics) ----
    const int partA_blocks = (N_INC + PAIRS_PER_BLOCK - 1) / PAIRS_PER_BLOCK;
    bucket_count_kernel<<<partA_blocks, 256, 0, stream>>>(
        hg_e, hg_v, g_dst, bktcnt_e, bktcnt_vhg, bktcnt_vg);
    bucket_scan_kernel<<<3, 256, 0, stream>>>(bktcnt_e, bstart_e,
                                              bktcnt_vhg, bstart_vhg,
                                              bktcnt_vg, bstart_vg);
    partitionA_kernel<<<partA_blocks, 256, 0, stream>>>(
        hg_v, hg_e, g_src, g_dst, bstart_e, bstart_vhg, bstart_vg,
        bcur_e, bcur_vhg, bcur_vg, rec_e, rec_vhg, rec_vg);
    partitionB_kernel<<<GRID_B, 256, 0, stream>>>(
        rec_e, rec_vhg, rec_vg, bstart_e, bstart_vhg, bstart_vg,
        deg_e, deg_vhg, deg_vg, off_e, off_vhg, off_vg,
        slot_e, slot_vhg, slot_vg);

    // ---- MLP (after B: h aliases rec region) ----
    mlp_kernel<<<N_VERTS / VPB, 256, 0, stream>>>(x, W1, b1, W2, b2, h);

    // ---- v2e gather ----
    const int ge_blocks = (int)(((size_t)N_HGE * 64 + 255) / 256);
    gather_e_kernel<<<ge_blocks, 256, 0, stream>>>(slot_e, off_e, deg_e, h, e_feat);

    // ---- fused e2v + graph gather + finalize ----
    const int vo_blocks = (int)(((size_t)N_VERTS * 64 + 255) / 256);
    vertex_out_kernel<<<vo_blocks, 256, 0, stream>>>(slot_vhg, off_vhg, deg_vhg,
                                                     slot_vg, off_vg, deg_vg,
                                                     e_feat, h, w, out);
}

// Round 2
// 559.387 us; speedup vs baseline: 1.7322x; 1.1562x over previous
//
#include <hip/hip_runtime.h>
#include <hip/hip_bf16.h>

// Problem constants (fixed by the reference setup)
#define N_VERTS   100000
#define N_HGE     10000
#define N_INC     1600000
#define N_EDGES   1600000
#define C_IN      256
#define C_MID     128
#define C_OUT     64
#define NEG       0.2f

// Radix-partition parameters.
#define EBSHIFT 6
#define NB_E    157              // ceil(10000/64)
#define VBSHIFT 9
#define NB_V    196              // ceil(100000/512)
#define NB_MAX  196
#define PAIRS_PER_BLOCK 4096     // 256 threads x 16
#define QP 16
#define BUCKET_CAP 16384

typedef __attribute__((ext_vector_type(8))) short  bf16x8;
typedef __attribute__((ext_vector_type(4))) float  f32x4;

// Truncation split: v = hi + lo with |err| <~ 2^-16 |v| (way below the
// 2^-9 noise floor vs the reference). hi = top-16 bits, lo = bf16(v-hi).
__device__ __forceinline__ void split1(float v, ushort& hi, ushort& lo) {
    const unsigned b = __float_as_uint(v);
    hi = (ushort)(b >> 16);
    const float r = v - __uint_as_float(b & 0xffff0000u);
    lo = (ushort)(__float_as_uint(r) >> 16);
}

// ---------------------------------------------------------------------------
// One-time weight prep: split W1/W2 into (hi,lo) bf16 and TRANSPOSE to [n][k]
// so MFMA B-fragments are 16B-contiguous reads.
// ---------------------------------------------------------------------------
__global__ __launch_bounds__(256) void
prep_w_kernel(const float* __restrict__ W1, const float* __restrict__ W2,
              ushort* __restrict__ W1t_h, ushort* __restrict__ W1t_l,
              ushort* __restrict__ W2t_h, ushort* __restrict__ W2t_l) {
    const int idx = blockIdx.x * 256 + threadIdx.x;
    if (idx < C_IN * C_MID) {                       // W1t[n][k], n<128,k<256
        const int n = idx >> 8, k = idx & 255;
        ushort hi, lo;
        split1(W1[k * C_MID + n], hi, lo);
        W1t_h[idx] = hi; W1t_l[idx] = lo;
    } else {
        const int j = idx - C_IN * C_MID;
        if (j < C_MID * C_OUT) {                    // W2t[n][k], n<64,k<128
            const int n = j >> 7, k = j & 127;
            ushort hi, lo;
            split1(W2[k * C_OUT + n], hi, lo);
            W2t_h[j] = hi; W2t_l[j] = lo;
        }
    }
}

// ---------------------------------------------------------------------------
// MFMA MLP: h = leaky_relu(x @ W1 + b1) @ W2 + b2, split-bf16 (3-term) so
// accuracy matches fp32 to ~2^-16. 128 verts/block, 4 waves in 2x2.
// Verified gfx950 16x16x32 bf16 fragment maps:
//   A: row = lane&15, k = (lane>>4)*8 + e ; B: col = lane&15, same k
//   C/D: col = lane&15, row = (lane>>4)*4 + reg   [learn_hip m89/m92]
// ---------------------------------------------------------------------------
#define MBM 128
__global__ __launch_bounds__(256) void
mlp_mfma_kernel(const float* __restrict__ x,
                const ushort* __restrict__ W1t_h, const ushort* __restrict__ W1t_l,
                const ushort* __restrict__ W2t_h, const ushort* __restrict__ W2t_l,
                const float* __restrict__ b1, const float* __restrict__ b2,
                float* __restrict__ h) {
    // union LDS: phase1 = xs_h/xs_l/ws_h/ws_l [128][72]; phase2 = mid_h/mid_l [128][136]
    __shared__ ushort buf[36864];                  // 72 KB
    ushort* xs_h = buf;                            // [128][72]
    ushort* xs_l = buf + 9216;
    ushort* ws_h = buf + 18432;                    // [128][72]
    ushort* ws_l = buf + 27648;
    ushort* mid_h = buf;                           // [128][136]
    ushort* mid_l = buf + 17408;

    const int t    = threadIdx.x;
    const int lane = t & 63;
    const int wid  = t >> 6;
    const int wr   = wid >> 1, wc = wid & 1;       // 2x2 wave grid
    const int v0   = blockIdx.x * MBM;
    const int rem  = N_VERTS - v0;                 // <128 only in last block
    const int l15  = lane & 15;
    const int lg   = lane >> 4;                    // 0..3

    f32x4 acc[4][4];
#pragma unroll
    for (int i = 0; i < 4; ++i)
#pragma unroll
        for (int j = 0; j < 4; ++j) acc[i][j] = (f32x4)0.f;

    // ---- layer 1: K tiled by 64 (4 tiles), split-bf16 staged in LDS ----
    for (int kt = 0; kt < 4; ++kt) {
        __syncthreads();
#pragma unroll
        for (int it = 0; it < 8; ++it) {           // x tile: 2048 float4
            const int idx = it * 256 + t;
            const int row = idx >> 4;
            const int c4  = (idx & 15) * 4;
            float4 v = make_float4(0.f, 0.f, 0.f, 0.f);
            if (row < rem)
                v = *(const float4*)&x[(size_t)(v0 + row) * C_IN + kt * 64 + c4];
            ushort h0,h1,h2,h3, l0,l1,l2,l3;
            split1(v.x, h0, l0); split1(v.y, h1, l1);
            split1(v.z, h2, l2); split1(v.w, h3, l3);
            uint2 ph, pl;
            ph.x = (unsigned)h0 | ((unsigned)h1 << 16);
            ph.y = (unsigned)h2 | ((unsigned)h3 << 16);
            pl.x = (unsigned)l0 | ((unsigned)l1 << 16);
            pl.y = (unsigned)l2 | ((unsigned)l3 << 16);
            *(uint2*)&xs_h[row * 72 + c4] = ph;
            *(uint2*)&xs_l[row * 72 + c4] = pl;
        }
#pragma unroll
        for (int it = 0; it < 8; ++it) {           // W1t tile: 2048 uint2 x2
            const int idx = it * 256 + t;
            const int n  = idx >> 4;
            const int c4 = (idx & 15) * 4;
            *(uint2*)&ws_h[n * 72 + c4] = *(const uint2*)&W1t_h[n * 256 + kt * 64 + c4];
            *(uint2*)&ws_l[n * 72 + c4] = *(const uint2*)&W1t_l[n * 256 + kt * 64 + c4];
        }
        __syncthreads();

#pragma unroll
        for (int ks = 0; ks < 2; ++ks) {
            const int k0 = ks * 32 + lg * 8;
            bf16x8 ah[4], al[4], bh[4], bl[4];
#pragma unroll
            for (int mf = 0; mf < 4; ++mf) {
                const int r = wr * 64 + mf * 16 + l15;
                ah[mf] = *(const bf16x8*)&xs_h[r * 72 + k0];
                al[mf] = *(const bf16x8*)&xs_l[r * 72 + k0];
            }
#pragma unroll
            for (int nf = 0; nf < 4; ++nf) {
                const int n = wc * 64 + nf * 16 + l15;
                bh[nf] = *(const bf16x8*)&ws_h[n * 72 + k0];
                bl[nf] = *(const bf16x8*)&ws_l[n * 72 + k0];
            }
#pragma unroll
            for (int mf = 0; mf < 4; ++mf)
#pragma unroll
                for (int nf = 0; nf < 4; ++nf) {
                    acc[mf][nf] = __builtin_amdgcn_mfma_f32_16x16x32_bf16(
                        ah[mf], bh[nf], acc[mf][nf], 0, 0, 0);
                    acc[mf][nf] = __builtin_amdgcn_mfma_f32_16x16x32_bf16(
                        al[mf], bh[nf], acc[mf][nf], 0, 0, 0);
                    acc[mf][nf] = __builtin_amdgcn_mfma_f32_16x16x32_bf16(
                        ah[mf], bl[nf], acc[mf][nf], 0, 0, 0);
                }
        }
    }
    __syncthreads();

    // ---- bias + leaky, split-write mid[m][k] (k = layer1 col) ----
#pragma unroll
    for (int nf = 0; nf < 4; ++nf) {
        const int col = wc * 64 + nf * 16 + l15;
        const float bias = b1[col];
#pragma unroll
        for (int mf = 0; mf < 4; ++mf)
#pragma unroll
            for (int j = 0; j < 4; ++j) {
                const int r = wr * 64 + mf * 16 + lg * 4 + j;
                float v = acc[mf][nf][j] + bias;
                v = v > 0.f ? v : NEG * v;
                ushort hi, lo;
                split1(v, hi, lo);
                mid_h[r * 136 + col] = hi;
                mid_l[r * 136 + col] = lo;
            }
    }
    __syncthreads();

    // ---- layer 2: K = 128, W2 fragments straight from global (L1-resident) ----
    f32x4 acc2[4][2];
#pragma unroll
    for (int i = 0; i < 4; ++i) { acc2[i][0] = (f32x4)0.f; acc2[i][1] = (f32x4)0.f; }

#pragma unroll
    for (int ks = 0; ks < 4; ++ks) {
        const int k0 = ks * 32 + lg * 8;
        bf16x8 ah[4], al[4];
#pragma unroll
        for (int mf = 0; mf < 4; ++mf) {
            const int r = wr * 64 + mf * 16 + l15;
            ah[mf] = *(const bf16x8*)&mid_h[r * 136 + k0];
            al[mf] = *(const bf16x8*)&mid_l[r * 136 + k0];
        }
#pragma unroll
        for (int nf = 0; nf < 2; ++nf) {
            const int n = wc * 32 + nf * 16 + l15;
            const bf16x8 bh = *(const bf16x8*)&W2t_h[n * 128 + k0];
            const bf16x8 bl = *(const bf16x8*)&W2t_l[n * 128 + k0];
#pragma unroll
            for (int mf = 0; mf < 4; ++mf) {
                acc2[mf][nf] = __builtin_amdgcn_mfma_f32_16x16x32_bf16(
                    ah[mf], bh, acc2[mf][nf], 0, 0, 0);
                acc2[mf][nf] = __builtin_amdgcn_mfma_f32_16x16x32_bf16(
                    al[mf], bh, acc2[mf][nf], 0, 0, 0);
                acc2[mf][nf] = __builtin_amdgcn_mfma_f32_16x16x32_bf16(
                    ah[mf], bl, acc2[mf][nf], 0, 0, 0);
            }
        }
    }

    // ---- store h (fp32, same layout as before) ----
#pragma unroll
    for (int nf = 0; nf < 2; ++nf) {
        const int col = wc * 32 + nf * 16 + l15;
        const float bias = b2[col];
#pragma unroll
        for (int mf = 0; mf < 4; ++mf)
#pragma unroll
            for (int j = 0; j < 4; ++j) {
                const int r = wr * 64 + mf * 16 + lg * 4 + j;
                if (r < rem)
                    h[(size_t)(v0 + r) * C_OUT + col] = acc2[mf][nf][j] + bias;
            }
    }
}

// ---------------------------------------------------------------------------
// Bucket-granularity count (one LDS histogram -> one global atomic per
// (block,bucket)).
// ---------------------------------------------------------------------------
__global__ __launch_bounds__(256) void
bucket_count_kernel(const int* __restrict__ hg_e, const int* __restrict__ hg_v,
                    const int* __restrict__ g_dst,
                    int* __restrict__ bktcnt_e, int* __restrict__ bktcnt_vhg,
                    int* __restrict__ bktcnt_vg) {
    __shared__ int hist[NB_MAX];
    const int t  = threadIdx.x;
    const int i0 = blockIdx.x * PAIRS_PER_BLOCK + t;

    for (int table = 0; table < 3; ++table) {
        const int* dsts; int* bktcnt; int shift, nb;
        if (table == 0)      { dsts = hg_e;  bktcnt = bktcnt_e;   shift = EBSHIFT; nb = NB_E; }
        else if (table == 1) { dsts = hg_v;  bktcnt = bktcnt_vhg; shift = VBSHIFT; nb = NB_V; }
        else                 { dsts = g_dst; bktcnt = bktcnt_vg;  shift = VBSHIFT; nb = NB_V; }

        if (t < nb) hist[t] = 0;
        __syncthreads();
#pragma unroll
        for (int q = 0; q < QP; ++q) {
            const int i = i0 + q * 256;
            if (i < N_INC) atomicAdd(&hist[dsts[i] >> shift], 1);
        }
        __syncthreads();
        if (t < nb) {
            const int c = hist[t];
            if (c) atomicAdd(&bktcnt[t], c);
        }
        __syncthreads();
    }
}

// Three tiny exclusive scans over bucket counts (<=196 each) in one dispatch.
__global__ __launch_bounds__(256) void
bucket_scan_kernel(const int* __restrict__ bktcnt_e,   int* __restrict__ bstart_e,
                   const int* __restrict__ bktcnt_vhg, int* __restrict__ bstart_vhg,
                   const int* __restrict__ bktcnt_vg,  int* __restrict__ bstart_vg) {
    __shared__ int s[256];
    const int* cnt; int* bs; int nb;
    if (blockIdx.x == 0)      { cnt = bktcnt_e;   bs = bstart_e;   nb = NB_E; }
    else if (blockIdx.x == 1) { cnt = bktcnt_vhg; bs = bstart_vhg; nb = NB_V; }
    else                      { cnt = bktcnt_vg;  bs = bstart_vg;  nb = NB_V; }
    const int t = threadIdx.x;
    const int own = (t < nb) ? cnt[t] : 0;
    s[t] = own;
    __syncthreads();
    for (int d = 1; d < 256; d <<= 1) {
        int v = (t >= d) ? s[t - d] : 0;
        __syncthreads();
        s[t] += v;
        __syncthreads();
    }
    if (t < nb) bs[t] = s[t] - own;   // exclusive
}

// ---------------------------------------------------------------------------
// Phase A: radix partition into bucket-dense record runs.
// ---------------------------------------------------------------------------
__global__ __launch_bounds__(256) void
partitionA_kernel(const int* __restrict__ hg_v, const int* __restrict__ hg_e,
                  const int* __restrict__ g_src, const int* __restrict__ g_dst,
                  const int* __restrict__ bstart_e, const int* __restrict__ bstart_vhg,
                  const int* __restrict__ bstart_vg,
                  int* __restrict__ bcur_e, int* __restrict__ bcur_vhg,
                  int* __restrict__ bcur_vg,
                  uint2* __restrict__ rec_e, uint2* __restrict__ rec_vhg,
                  uint2* __restrict__ rec_vg) {
    __shared__ int hist[NB_MAX];
    __shared__ int gb[NB_MAX];
    __shared__ int bb[NB_MAX];
    const int t  = threadIdx.x;
    const int i0 = blockIdx.x * PAIRS_PER_BLOCK + t;

    for (int table = 0; table < 3; ++table) {
        const int *dsts, *pays, *bstart;
        int *bcur; uint2* rec;
        int shift, nb;
        if (table == 0)      { dsts = hg_e;  pays = hg_v;  bstart = bstart_e;
                               bcur = bcur_e;   rec = rec_e;   shift = EBSHIFT; nb = NB_E; }
        else if (table == 1) { dsts = hg_v;  pays = hg_e;  bstart = bstart_vhg;
                               bcur = bcur_vhg; rec = rec_vhg; shift = VBSHIFT; nb = NB_V; }
        else                 { dsts = g_dst; pays = g_src; bstart = bstart_vg;
                               bcur = bcur_vg;  rec = rec_vg;  shift = VBSHIFT; nb = NB_V; }

        if (t < nb) hist[t] = 0;
        __syncthreads();

        int d[QP], p[QP], bk[QP], rk[QP];
#pragma unroll
        for (int q = 0; q < QP; ++q) {
            const int i = i0 + q * 256;
            if (i < N_INC) {
                d[q]  = dsts[i];
                p[q]  = pays[i];
                bk[q] = d[q] >> shift;
                rk[q] = atomicAdd(&hist[bk[q]], 1);
            } else bk[q] = -1;
        }
        __syncthreads();

        if (t < nb) {
            gb[t] = atomicAdd(&bcur[t], hist[t]);
            bb[t] = bstart[t];
        }
        __syncthreads();

#pragma unroll
        for (int q = 0; q < QP; ++q) {
            if (bk[q] >= 0) {
                const int pos = bb[bk[q]] + gb[bk[q]] + rk[q];
                rec[pos] = make_uint2((unsigned)d[q], (unsigned)p[q]);
            }
        }
        __syncthreads();
    }
}

// ---------------------------------------------------------------------------
// Phase B: per-bucket CSR derivation + dense slot build in LDS.
// ---------------------------------------------------------------------------
#define GRID_B (NB_E + 2 * NB_V)
__global__ __launch_bounds__(256) void
partitionB_kernel(const uint2* __restrict__ rec_e, const uint2* __restrict__ rec_vhg,
                  const uint2* __restrict__ rec_vg,
                  const int* __restrict__ bstart_e, const int* __restrict__ bstart_vhg,
                  const int* __restrict__ bstart_vg,
                  int* __restrict__ deg_e, int* __restrict__ deg_vhg,
                  int* __restrict__ deg_vg,
                  int* __restrict__ off_e, int* __restrict__ off_vhg,
                  int* __restrict__ off_vg,
                  int* __restrict__ slot_e, int* __restrict__ slot_vhg,
                  int* __restrict__ slot_vg) {
    __shared__ int slotbuf[BUCKET_CAP];   // 64 KB
    __shared__ int cnt_l[1 << VBSHIFT];   // 2 KB
    __shared__ int cur_l[1 << VBSHIFT];   // 2 KB
    __shared__ int part[256];             // 1 KB

    int blk = blockIdx.x;
    const uint2* rec; const int* bstart; int* deg; int* off; int* slot;
    int b, shift, ndst, nb;
    if (blk < NB_E) {
        rec = rec_e; bstart = bstart_e; deg = deg_e; off = off_e; slot = slot_e;
        shift = EBSHIFT; ndst = N_HGE; nb = NB_E; b = blk;
    } else if (blk < NB_E + NB_V) {
        rec = rec_vhg; bstart = bstart_vhg; deg = deg_vhg; off = off_vhg; slot = slot_vhg;
        shift = VBSHIFT; ndst = N_VERTS; nb = NB_V; b = blk - NB_E;
    } else {
        rec = rec_vg; bstart = bstart_vg; deg = deg_vg; off = off_vg; slot = slot_vg;
        shift = VBSHIFT; ndst = N_VERTS; nb = NB_V; b = blk - NB_E - NB_V;
    }
    const int t    = threadIdx.x;
    const int dlo  = b << shift;
    const int nd   = 1 << shift;
    const int ndc  = min(nd, ndst - dlo);
    const int bs   = bstart[b];
    const int be   = (b == nb - 1) ? N_INC : bstart[b + 1];
    const int bcnt = be - bs;

    for (int j = t; j < nd; j += 256) cnt_l[j] = 0;
    __syncthreads();
    for (int i = bs + t; i < be; i += 256)
        atomicAdd(&cnt_l[(int)rec[i].x - dlo], 1);
    __syncthreads();

    const int chunk = (nd + 255) / 256;     // 1 or 2
    const int lo = t * chunk;
    const int hi = min(lo + chunk, nd);
    int s = 0;
    for (int j = lo; j < hi; ++j) s += cnt_l[j];
    part[t] = s;
    __syncthreads();
    for (int d = 1; d < 256; d <<= 1) {
        int v = (t >= d) ? part[t - d] : 0;
        __syncthreads();
        part[t] += v;
        __syncthreads();
    }
    int run = (t > 0) ? part[t - 1] : 0;
    for (int j = lo; j < hi; ++j) { cur_l[j] = run; run += cnt_l[j]; }
    __syncthreads();

    for (int j = t; j < ndc; j += 256) {
        deg[dlo + j] = cnt_l[j];
        off[dlo + j] = bs + cur_l[j];
    }
    __syncthreads();

    if (bcnt <= BUCKET_CAP) {
        for (int i = bs + t; i < be; i += 256) {
            const uint2 r = rec[i];
            const int lpos = atomicAdd(&cur_l[(int)r.x - dlo], 1);
            slotbuf[lpos] = (int)r.y;
        }
        __syncthreads();
        for (int i = t; i < bcnt; i += 256)
            slot[bs + i] = slotbuf[i];
    } else {
        for (int i = bs + t; i < be; i += 256) {
            const uint2 r = rec[i];
            const int pos = bs + atomicAdd(&cur_l[(int)r.x - dlo], 1);
            slot[pos] = (int)r.y;
        }
    }
}

// ---------------------------------------------------------------------------
// v2e gather: one wave per hyperedge, lane = channel.
// ---------------------------------------------------------------------------
__global__ void gather_e_kernel(const int* __restrict__ slot, const int* __restrict__ off,
                                const int* __restrict__ deg, const float* __restrict__ h,
                                float* __restrict__ e_feat) {
    const int wid  = (blockIdx.x * blockDim.x + threadIdx.x) >> 6;
    const int lane = threadIdx.x & 63;
    if (wid >= N_HGE) return;
    const int n    = deg[wid];
    const int base = off[wid];
    float acc = 0.f;
    int j = 0;
    for (; j + 4 <= n; j += 4) {
        const int v0 = slot[base + j + 0];
        const int v1 = slot[base + j + 1];
        const int v2 = slot[base + j + 2];
        const int v3 = slot[base + j + 3];
        const float r0 = h[(size_t)v0 * C_OUT + lane];
        const float r1 = h[(size_t)v1 * C_OUT + lane];
        const float r2 = h[(size_t)v2 * C_OUT + lane];
        const float r3 = h[(size_t)v3 * C_OUT + lane];
        acc += (r0 + r1) + (r2 + r3);
    }
    for (; j < n; ++j)
        acc += h[(size_t)slot[base + j] * C_OUT + lane];
    e_feat[(size_t)wid * C_OUT + lane] = acc / fmaxf((float)n, 1.f);
}

// ---------------------------------------------------------------------------
// Fused per-vertex epilogue.
// ---------------------------------------------------------------------------
__global__ void vertex_out_kernel(const int* __restrict__ slot_vhg,
                                  const int* __restrict__ off_vhg,
                                  const int* __restrict__ deg_vhg,
                                  const int* __restrict__ slot_vg,
                                  const int* __restrict__ off_vg,
                                  const int* __restrict__ deg_vg,
                                  const float* __restrict__ e_feat,
                                  const float* __restrict__ h,
                                  const float* __restrict__ w,
                                  float* __restrict__ out) {
    const int wid  = (blockIdx.x * blockDim.x + threadIdx.x) >> 6;
    const int lane = threadIdx.x & 63;
    if (wid >= N_VERTS) return;

    float acc_hg = 0.f;
    {
        const int n = deg_vhg[wid];
        const int base = off_vhg[wid];
        int j = 0;
        for (; j + 4 <= n; j += 4) {
            const int e0 = slot_vhg[base + j + 0];
            const int e1 = slot_vhg[base + j + 1];
            const int e2 = slot_vhg[base + j + 2];
            const int e3 = slot_vhg[base + j + 3];
            const float r0 = e_feat[(size_t)e0 * C_OUT + lane];
            const float r1 = e_feat[(size_t)e1 * C_OUT + lane];
            const float r2 = e_feat[(size_t)e2 * C_OUT + lane];
            const float r3 = e_feat[(size_t)e3 * C_OUT + lane];
            acc_hg += (r0 + r1) + (r2 + r3);
        }
        for (; j < n; ++j)
            acc_hg += e_feat[(size_t)slot_vhg[base + j] * C_OUT + lane];
        acc_hg /= fmaxf((float)n, 1.f);
    }

    float acc_g = 0.f;
    {
        const int n = deg_vg[wid];
        const int base = off_vg[wid];
        int j = 0;
        for (; j + 4 <= n; j += 4) {
            const int v0 = slot_vg[base + j + 0];
            const int v1 = slot_vg[base + j + 1];
            const int v2 = slot_vg[base + j + 2];
            const int v3 = slot_vg[base + j + 3];
            const float r0 = h[(size_t)v0 * C_OUT + lane];
            const float r1 = h[(size_t)v1 * C_OUT + lane];
            const float r2 = h[(size_t)v2 * C_OUT + lane];
            const float r3 = h[(size_t)v3 * C_OUT + lane];
            acc_g += (r0 + r1) + (r2 + r3);
        }
        for (; j < n; ++j)
            acc_g += h[(size_t)slot_vg[base + j] * C_OUT + lane];
        acc_g /= fmaxf((float)n, 1.f);
    }

    const float w0 = w[0], w1 = w[1];
    const float m  = fmaxf(w0, w1);
    const float e0 = __expf(w0 - m), e1 = __expf(w1 - m);
    const float sw0 = e0 / (e0 + e1), sw1 = e1 / (e0 + e1);

    const float hv = h[(size_t)wid * C_OUT + lane];
    float o = sw0 * 0.5f * (acc_g + acc_hg) + sw1 * hv;
    o = o > 0.f ? o : NEG * o;
    out[(size_t)wid * C_OUT + lane] = o;
}

// ---------------------------------------------------------------------------
extern "C" void kernel_launch(void* const* d_in, const int* in_sizes, int n_in,
                              void* d_out, int out_size, void* d_ws, size_t ws_size,
                              hipStream_t stream) {
    const float* x    = (const float*)d_in[0];
    const float* W1   = (const float*)d_in[1];
    const float* b1   = (const float*)d_in[2];
    const float* W2   = (const float*)d_in[3];
    const float* b2   = (const float*)d_in[4];
    const float* w    = (const float*)d_in[5];
    const int*  hg_v  = (const int*)d_in[6];
    const int*  hg_e  = (const int*)d_in[7];
    const int*  g_src = (const int*)d_in[8];
    const int*  g_dst = (const int*)d_in[9];
    float* out = (float*)d_out;

    // ---- workspace layout ----
    // Region R (reused): rec arrays during CSR build, then h + e_feat + Wsplit.
    uint2* rec_e   = (uint2*)d_ws;                 // N_INC   (12.8 MB)
    uint2* rec_vhg = rec_e   + N_INC;              // N_INC   (12.8 MB)
    uint2* rec_vg  = rec_vhg + N_INC;              // N_EDGES (12.8 MB)
    float* h       = (float*)d_ws;                 // N_VERTS*64 (25.6 MB) - after B
    float* e_feat  = h + (size_t)N_VERTS * C_OUT;  // N_HGE*64   (2.56 MB) - after B
    // split weights live after e_feat (28.16 MB), inside dead rec_vg region
    ushort* W1t_h  = (ushort*)(e_feat + (size_t)N_HGE * C_OUT);  // 64 KB
    ushort* W1t_l  = W1t_h + C_IN * C_MID;                       // 64 KB
    ushort* W2t_h  = W1t_l + C_IN * C_MID;                       // 16 KB
    ushort* W2t_l  = W2t_h + C_MID * C_OUT;                      // 16 KB

    int* slot_e    = (int*)(rec_vg + N_EDGES);     // N_INC
    int* slot_vhg  = slot_e   + N_INC;             // N_INC
    int* slot_vg   = slot_vhg + N_INC;             // N_EDGES
    // zeroed int region:
    int* bktcnt_e   = slot_vg  + N_EDGES;          // NB_E
    int* bktcnt_vhg = bktcnt_e   + NB_E;           // NB_V
    int* bktcnt_vg  = bktcnt_vhg + NB_V;           // NB_V
    int* bcur_e     = bktcnt_vg  + NB_V;           // NB_E
    int* bcur_vhg   = bcur_e     + NB_E;           // NB_V
    int* bcur_vg    = bcur_vhg   + NB_V;           // NB_V
    // not zeroed:
    int* bstart_e   = bcur_vg    + NB_V;           // NB_E
    int* bstart_vhg = bstart_e   + NB_E;           // NB_V
    int* bstart_vg  = bstart_vhg + NB_V;           // NB_V
    int* deg_e      = bstart_vg  + NB_V;           // N_HGE
    int* deg_vhg    = deg_e      + N_HGE;          // N_VERTS
    int* deg_vg     = deg_vhg    + N_VERTS;        // N_VERTS
    int* off_e      = deg_vg     + N_VERTS;        // N_HGE
    int* off_vhg    = off_e      + N_HGE;          // N_VERTS
    int* off_vg     = off_vhg    + N_VERTS;        // N_VERTS

    const size_t zero_elems = 2 * ((size_t)NB_E + 2 * (size_t)NB_V);
    hipMemsetAsync(bktcnt_e, 0, zero_elems * sizeof(int), stream);

    // ---- CSR build ----
    const int partA_blocks = (N_INC + PAIRS_PER_BLOCK - 1) / PAIRS_PER_BLOCK;
    bucket_count_kernel<<<partA_blocks, 256, 0, stream>>>(
        hg_e, hg_v, g_dst, bktcnt_e, bktcnt_vhg, bktcnt_vg);
    bucket_scan_kernel<<<3, 256, 0, stream>>>(bktcnt_e, bstart_e,
                                              bktcnt_vhg, bstart_vhg,
                                              bktcnt_vg, bstart_vg);
    partitionA_kernel<<<partA_blocks, 256, 0, stream>>>(
        hg_v, hg_e, g_src, g_dst, bstart_e, bstart_vhg, bstart_vg,
        bcur_e, bcur_vhg, bcur_vg, rec_e, rec_vhg, rec_vg);
    partitionB_kernel<<<GRID_B, 256, 0, stream>>>(
        rec_e, rec_vhg, rec_vg, bstart_e, bstart_vhg, bstart_vg,
        deg_e, deg_vhg, deg_vg, off_e, off_vhg, off_vg,
        slot_e, slot_vhg, slot_vg);

    // ---- weight split (after B: rec_vg region dead) ----
    prep_w_kernel<<<(C_IN * C_MID + C_MID * C_OUT + 255) / 256, 256, 0, stream>>>(
        W1, W2, W1t_h, W1t_l, W2t_h, W2t_l);

    // ---- MFMA MLP (h aliases rec region) ----
    mlp_mfma_kernel<<<(N_VERTS + MBM - 1) / MBM, 256, 0, stream>>>(
        x, W1t_h, W1t_l, W2t_h, W2t_l, b1, b2, h);

    // ---- v2e gather ----
    const int ge_blocks = (int)(((size_t)N_HGE * 64 + 255) / 256);
    gather_e_kernel<<<ge_blocks, 256, 0, stream>>>(slot_e, off_e, deg_e, h, e_feat);

    // ---- fused e2v + graph gather + finalize ----
    const int vo_blocks = (int)(((size_t)N_VERTS * 64 + 255) / 256);
    vertex_out_kernel<<<vo_blocks, 256, 0, stream>>>(slot_vhg, off_vhg, deg_vhg,
                                                     slot_vg, off_vg, deg_vg,
                                                     e_feat, h, w, out);
}

// Round 3
// 519.585 us; speedup vs baseline: 1.8649x; 1.0766x over previous
//
#include <hip/hip_runtime.h>
#include <hip/hip_bf16.h>
#include <hip/hip_fp16.h>

// Problem constants (fixed by the reference setup)
#define N_VERTS   100000
#define N_HGE     10000
#define N_INC     1600000
#define N_EDGES   1600000
#define C_IN      256
#define C_MID     128
#define C_OUT     64
#define NEG       0.2f

// Radix-partition parameters.
#define EBSHIFT 6
#define NB_E    157              // ceil(10000/64)
#define VBSHIFT 9
#define NB_V    196              // ceil(100000/512)
#define NB_MAX  196
#define PAIRS_PER_BLOCK 4096     // 256 threads x 16
#define QP 16
#define BUCKET_CAP 16384

typedef __attribute__((ext_vector_type(8))) short  bf16x8;
typedef __attribute__((ext_vector_type(4))) float  f32x4;

// Truncation split: v = hi + lo with |err| <~ 2^-16 |v|.
__device__ __forceinline__ void split1(float v, ushort& hi, ushort& lo) {
    const unsigned b = __float_as_uint(v);
    hi = (ushort)(b >> 16);
    const float r = v - __uint_as_float(b & 0xffff0000u);
    lo = (ushort)(__float_as_uint(r) >> 16);
}

// ---------------------------------------------------------------------------
// One-time weight prep: split W1/W2 into (hi,lo) bf16 and TRANSPOSE to [n][k].
// ---------------------------------------------------------------------------
__global__ __launch_bounds__(256) void
prep_w_kernel(const float* __restrict__ W1, const float* __restrict__ W2,
              ushort* __restrict__ W1t_h, ushort* __restrict__ W1t_l,
              ushort* __restrict__ W2t_h, ushort* __restrict__ W2t_l) {
    const int idx = blockIdx.x * 256 + threadIdx.x;
    if (idx < C_IN * C_MID) {                       // W1t[n][k], n<128,k<256
        const int n = idx >> 8, k = idx & 255;
        ushort hi, lo;
        split1(W1[k * C_MID + n], hi, lo);
        W1t_h[idx] = hi; W1t_l[idx] = lo;
    } else {
        const int j = idx - C_IN * C_MID;
        if (j < C_MID * C_OUT) {                    // W2t[n][k], n<64,k<128
            const int n = j >> 7, k = j & 127;
            ushort hi, lo;
            split1(W2[k * C_OUT + n], hi, lo);
            W2t_h[j] = hi; W2t_l[j] = lo;
        }
    }
}

// ---------------------------------------------------------------------------
// MFMA MLP: h = leaky_relu(x @ W1 + b1) @ W2 + b2, split-bf16 (3-term).
// Output h stored as fp16 (gather payload downstream; 2^-11 rel error).
// ---------------------------------------------------------------------------
#define MBM 128
__global__ __launch_bounds__(256) void
mlp_mfma_kernel(const float* __restrict__ x,
                const ushort* __restrict__ W1t_h, const ushort* __restrict__ W1t_l,
                const ushort* __restrict__ W2t_h, const ushort* __restrict__ W2t_l,
                const float* __restrict__ b1, const float* __restrict__ b2,
                __half* __restrict__ h) {
    // union LDS: phase1 = xs_h/xs_l/ws_h/ws_l [128][72]; phase2 = mid_h/mid_l [128][136]
    __shared__ ushort buf[36864];                  // 72 KB
    ushort* xs_h = buf;                            // [128][72]
    ushort* xs_l = buf + 9216;
    ushort* ws_h = buf + 18432;                    // [128][72]
    ushort* ws_l = buf + 27648;
    ushort* mid_h = buf;                           // [128][136]
    ushort* mid_l = buf + 17408;

    const int t    = threadIdx.x;
    const int lane = t & 63;
    const int wid  = t >> 6;
    const int wr   = wid >> 1, wc = wid & 1;       // 2x2 wave grid
    const int v0   = blockIdx.x * MBM;
    const int rem  = N_VERTS - v0;                 // <128 only in last block
    const int l15  = lane & 15;
    const int lg   = lane >> 4;                    // 0..3

    f32x4 acc[4][4];
#pragma unroll
    for (int i = 0; i < 4; ++i)
#pragma unroll
        for (int j = 0; j < 4; ++j) acc[i][j] = (f32x4)0.f;

    // ---- layer 1: K tiled by 64 (4 tiles), split-bf16 staged in LDS ----
    for (int kt = 0; kt < 4; ++kt) {
        __syncthreads();
#pragma unroll
        for (int it = 0; it < 8; ++it) {           // x tile: 2048 float4
            const int idx = it * 256 + t;
            const int row = idx >> 4;
            const int c4  = (idx & 15) * 4;
            float4 v = make_float4(0.f, 0.f, 0.f, 0.f);
            if (row < rem)
                v = *(const float4*)&x[(size_t)(v0 + row) * C_IN + kt * 64 + c4];
            ushort h0,h1,h2,h3, l0,l1,l2,l3;
            split1(v.x, h0, l0); split1(v.y, h1, l1);
            split1(v.z, h2, l2); split1(v.w, h3, l3);
            uint2 ph, pl;
            ph.x = (unsigned)h0 | ((unsigned)h1 << 16);
            ph.y = (unsigned)h2 | ((unsigned)h3 << 16);
            pl.x = (unsigned)l0 | ((unsigned)l1 << 16);
            pl.y = (unsigned)l2 | ((unsigned)l3 << 16);
            *(uint2*)&xs_h[row * 72 + c4] = ph;
            *(uint2*)&xs_l[row * 72 + c4] = pl;
        }
#pragma unroll
        for (int it = 0; it < 8; ++it) {           // W1t tile
            const int idx = it * 256 + t;
            const int n  = idx >> 4;
            const int c4 = (idx & 15) * 4;
            *(uint2*)&ws_h[n * 72 + c4] = *(const uint2*)&W1t_h[n * 256 + kt * 64 + c4];
            *(uint2*)&ws_l[n * 72 + c4] = *(const uint2*)&W1t_l[n * 256 + kt * 64 + c4];
        }
        __syncthreads();

#pragma unroll
        for (int ks = 0; ks < 2; ++ks) {
            const int k0 = ks * 32 + lg * 8;
            bf16x8 ah[4], al[4], bh[4], bl[4];
#pragma unroll
            for (int mf = 0; mf < 4; ++mf) {
                const int r = wr * 64 + mf * 16 + l15;
                ah[mf] = *(const bf16x8*)&xs_h[r * 72 + k0];
                al[mf] = *(const bf16x8*)&xs_l[r * 72 + k0];
            }
#pragma unroll
            for (int nf = 0; nf < 4; ++nf) {
                const int n = wc * 64 + nf * 16 + l15;
                bh[nf] = *(const bf16x8*)&ws_h[n * 72 + k0];
                bl[nf] = *(const bf16x8*)&ws_l[n * 72 + k0];
            }
#pragma unroll
            for (int mf = 0; mf < 4; ++mf)
#pragma unroll
                for (int nf = 0; nf < 4; ++nf) {
                    acc[mf][nf] = __builtin_amdgcn_mfma_f32_16x16x32_bf16(
                        ah[mf], bh[nf], acc[mf][nf], 0, 0, 0);
                    acc[mf][nf] = __builtin_amdgcn_mfma_f32_16x16x32_bf16(
                        al[mf], bh[nf], acc[mf][nf], 0, 0, 0);
                    acc[mf][nf] = __builtin_amdgcn_mfma_f32_16x16x32_bf16(
                        ah[mf], bl[nf], acc[mf][nf], 0, 0, 0);
                }
        }
    }
    __syncthreads();

    // ---- bias + leaky, split-write mid[m][k] ----
#pragma unroll
    for (int nf = 0; nf < 4; ++nf) {
        const int col = wc * 64 + nf * 16 + l15;
        const float bias = b1[col];
#pragma unroll
        for (int mf = 0; mf < 4; ++mf)
#pragma unroll
            for (int j = 0; j < 4; ++j) {
                const int r = wr * 64 + mf * 16 + lg * 4 + j;
                float v = acc[mf][nf][j] + bias;
                v = v > 0.f ? v : NEG * v;
                ushort hi, lo;
                split1(v, hi, lo);
                mid_h[r * 136 + col] = hi;
                mid_l[r * 136 + col] = lo;
            }
    }
    __syncthreads();

    // ---- layer 2: K = 128 ----
    f32x4 acc2[4][2];
#pragma unroll
    for (int i = 0; i < 4; ++i) { acc2[i][0] = (f32x4)0.f; acc2[i][1] = (f32x4)0.f; }

#pragma unroll
    for (int ks = 0; ks < 4; ++ks) {
        const int k0 = ks * 32 + lg * 8;
        bf16x8 ah[4], al[4];
#pragma unroll
        for (int mf = 0; mf < 4; ++mf) {
            const int r = wr * 64 + mf * 16 + l15;
            ah[mf] = *(const bf16x8*)&mid_h[r * 136 + k0];
            al[mf] = *(const bf16x8*)&mid_l[r * 136 + k0];
        }
#pragma unroll
        for (int nf = 0; nf < 2; ++nf) {
            const int n = wc * 32 + nf * 16 + l15;
            const bf16x8 bh = *(const bf16x8*)&W2t_h[n * 128 + k0];
            const bf16x8 bl = *(const bf16x8*)&W2t_l[n * 128 + k0];
#pragma unroll
            for (int mf = 0; mf < 4; ++mf) {
                acc2[mf][nf] = __builtin_amdgcn_mfma_f32_16x16x32_bf16(
                    ah[mf], bh, acc2[mf][nf], 0, 0, 0);
                acc2[mf][nf] = __builtin_amdgcn_mfma_f32_16x16x32_bf16(
                    al[mf], bh, acc2[mf][nf], 0, 0, 0);
                acc2[mf][nf] = __builtin_amdgcn_mfma_f32_16x16x32_bf16(
                    ah[mf], bl, acc2[mf][nf], 0, 0, 0);
            }
        }
    }

    // ---- store h as fp16 ----
#pragma unroll
    for (int nf = 0; nf < 2; ++nf) {
        const int col = wc * 32 + nf * 16 + l15;
        const float bias = b2[col];
#pragma unroll
        for (int mf = 0; mf < 4; ++mf)
#pragma unroll
            for (int j = 0; j < 4; ++j) {
                const int r = wr * 64 + mf * 16 + lg * 4 + j;
                if (r < rem)
                    h[(size_t)(v0 + r) * C_OUT + col] =
                        __float2half_rn(acc2[mf][nf][j] + bias);
            }
    }
}

// ---------------------------------------------------------------------------
// Bucket-granularity count.
// ---------------------------------------------------------------------------
__global__ __launch_bounds__(256) void
bucket_count_kernel(const int* __restrict__ hg_e, const int* __restrict__ hg_v,
                    const int* __restrict__ g_dst,
                    int* __restrict__ bktcnt_e, int* __restrict__ bktcnt_vhg,
                    int* __restrict__ bktcnt_vg) {
    __shared__ int hist[NB_MAX];
    const int t  = threadIdx.x;
    const int i0 = blockIdx.x * PAIRS_PER_BLOCK + t;

    for (int table = 0; table < 3; ++table) {
        const int* dsts; int* bktcnt; int shift, nb;
        if (table == 0)      { dsts = hg_e;  bktcnt = bktcnt_e;   shift = EBSHIFT; nb = NB_E; }
        else if (table == 1) { dsts = hg_v;  bktcnt = bktcnt_vhg; shift = VBSHIFT; nb = NB_V; }
        else                 { dsts = g_dst; bktcnt = bktcnt_vg;  shift = VBSHIFT; nb = NB_V; }

        if (t < nb) hist[t] = 0;
        __syncthreads();
#pragma unroll
        for (int q = 0; q < QP; ++q) {
            const int i = i0 + q * 256;
            if (i < N_INC) atomicAdd(&hist[dsts[i] >> shift], 1);
        }
        __syncthreads();
        if (t < nb) {
            const int c = hist[t];
            if (c) atomicAdd(&bktcnt[t], c);
        }
        __syncthreads();
    }
}

// Three tiny exclusive scans over bucket counts (<=196 each) in one dispatch.
__global__ __launch_bounds__(256) void
bucket_scan_kernel(const int* __restrict__ bktcnt_e,   int* __restrict__ bstart_e,
                   const int* __restrict__ bktcnt_vhg, int* __restrict__ bstart_vhg,
                   const int* __restrict__ bktcnt_vg,  int* __restrict__ bstart_vg) {
    __shared__ int s[256];
    const int* cnt; int* bs; int nb;
    if (blockIdx.x == 0)      { cnt = bktcnt_e;   bs = bstart_e;   nb = NB_E; }
    else if (blockIdx.x == 1) { cnt = bktcnt_vhg; bs = bstart_vhg; nb = NB_V; }
    else                      { cnt = bktcnt_vg;  bs = bstart_vg;  nb = NB_V; }
    const int t = threadIdx.x;
    const int own = (t < nb) ? cnt[t] : 0;
    s[t] = own;
    __syncthreads();
    for (int d = 1; d < 256; d <<= 1) {
        int v = (t >= d) ? s[t - d] : 0;
        __syncthreads();
        s[t] += v;
        __syncthreads();
    }
    if (t < nb) bs[t] = s[t] - own;   // exclusive
}

// ---------------------------------------------------------------------------
// Phase A: radix partition into bucket-dense record runs.
// ---------------------------------------------------------------------------
__global__ __launch_bounds__(256) void
partitionA_kernel(const int* __restrict__ hg_v, const int* __restrict__ hg_e,
                  const int* __restrict__ g_src, const int* __restrict__ g_dst,
                  const int* __restrict__ bstart_e, const int* __restrict__ bstart_vhg,
                  const int* __restrict__ bstart_vg,
                  int* __restrict__ bcur_e, int* __restrict__ bcur_vhg,
                  int* __restrict__ bcur_vg,
                  uint2* __restrict__ rec_e, uint2* __restrict__ rec_vhg,
                  uint2* __restrict__ rec_vg) {
    __shared__ int hist[NB_MAX];
    __shared__ int gb[NB_MAX];
    __shared__ int bb[NB_MAX];
    const int t  = threadIdx.x;
    const int i0 = blockIdx.x * PAIRS_PER_BLOCK + t;

    for (int table = 0; table < 3; ++table) {
        const int *dsts, *pays, *bstart;
        int *bcur; uint2* rec;
        int shift, nb;
        if (table == 0)      { dsts = hg_e;  pays = hg_v;  bstart = bstart_e;
                               bcur = bcur_e;   rec = rec_e;   shift = EBSHIFT; nb = NB_E; }
        else if (table == 1) { dsts = hg_v;  pays = hg_e;  bstart = bstart_vhg;
                               bcur = bcur_vhg; rec = rec_vhg; shift = VBSHIFT; nb = NB_V; }
        else                 { dsts = g_dst; pays = g_src; bstart = bstart_vg;
                               bcur = bcur_vg;  rec = rec_vg;  shift = VBSHIFT; nb = NB_V; }

        if (t < nb) hist[t] = 0;
        __syncthreads();

        int d[QP], p[QP], bk[QP], rk[QP];
#pragma unroll
        for (int q = 0; q < QP; ++q) {
            const int i = i0 + q * 256;
            if (i < N_INC) {
                d[q]  = dsts[i];
                p[q]  = pays[i];
                bk[q] = d[q] >> shift;
                rk[q] = atomicAdd(&hist[bk[q]], 1);
            } else bk[q] = -1;
        }
        __syncthreads();

        if (t < nb) {
            gb[t] = atomicAdd(&bcur[t], hist[t]);
            bb[t] = bstart[t];
        }
        __syncthreads();

#pragma unroll
        for (int q = 0; q < QP; ++q) {
            if (bk[q] >= 0) {
                const int pos = bb[bk[q]] + gb[bk[q]] + rk[q];
                rec[pos] = make_uint2((unsigned)d[q], (unsigned)p[q]);
            }
        }
        __syncthreads();
    }
}

// ---------------------------------------------------------------------------
// Phase B: per-bucket CSR derivation + dense slot build in LDS.
// ---------------------------------------------------------------------------
#define GRID_B (NB_E + 2 * NB_V)
__global__ __launch_bounds__(256) void
partitionB_kernel(const uint2* __restrict__ rec_e, const uint2* __restrict__ rec_vhg,
                  const uint2* __restrict__ rec_vg,
                  const int* __restrict__ bstart_e, const int* __restrict__ bstart_vhg,
                  const int* __restrict__ bstart_vg,
                  int* __restrict__ deg_e, int* __restrict__ deg_vhg,
                  int* __restrict__ deg_vg,
                  int* __restrict__ off_e, int* __restrict__ off_vhg,
                  int* __restrict__ off_vg,
                  int* __restrict__ slot_e, int* __restrict__ slot_vhg,
                  int* __restrict__ slot_vg) {
    __shared__ int slotbuf[BUCKET_CAP];   // 64 KB
    __shared__ int cnt_l[1 << VBSHIFT];   // 2 KB
    __shared__ int cur_l[1 << VBSHIFT];   // 2 KB
    __shared__ int part[256];             // 1 KB

    int blk = blockIdx.x;
    const uint2* rec; const int* bstart; int* deg; int* off; int* slot;
    int b, shift, ndst, nb;
    if (blk < NB_E) {
        rec = rec_e; bstart = bstart_e; deg = deg_e; off = off_e; slot = slot_e;
        shift = EBSHIFT; ndst = N_HGE; nb = NB_E; b = blk;
    } else if (blk < NB_E + NB_V) {
        rec = rec_vhg; bstart = bstart_vhg; deg = deg_vhg; off = off_vhg; slot = slot_vhg;
        shift = VBSHIFT; ndst = N_VERTS; nb = NB_V; b = blk - NB_E;
    } else {
        rec = rec_vg; bstart = bstart_vg; deg = deg_vg; off = off_vg; slot = slot_vg;
        shift = VBSHIFT; ndst = N_VERTS; nb = NB_V; b = blk - NB_E - NB_V;
    }
    const int t    = threadIdx.x;
    const int dlo  = b << shift;
    const int nd   = 1 << shift;
    const int ndc  = min(nd, ndst - dlo);
    const int bs   = bstart[b];
    const int be   = (b == nb - 1) ? N_INC : bstart[b + 1];
    const int bcnt = be - bs;

    for (int j = t; j < nd; j += 256) cnt_l[j] = 0;
    __syncthreads();
    for (int i = bs + t; i < be; i += 256)
        atomicAdd(&cnt_l[(int)rec[i].x - dlo], 1);
    __syncthreads();

    const int chunk = (nd + 255) / 256;     // 1 or 2
    const int lo = t * chunk;
    const int hi = min(lo + chunk, nd);
    int s = 0;
    for (int j = lo; j < hi; ++j) s += cnt_l[j];
    part[t] = s;
    __syncthreads();
    for (int d = 1; d < 256; d <<= 1) {
        int v = (t >= d) ? part[t - d] : 0;
        __syncthreads();
        part[t] += v;
        __syncthreads();
    }
    int run = (t > 0) ? part[t - 1] : 0;
    for (int j = lo; j < hi; ++j) { cur_l[j] = run; run += cnt_l[j]; }
    __syncthreads();

    for (int j = t; j < ndc; j += 256) {
        deg[dlo + j] = cnt_l[j];
        off[dlo + j] = bs + cur_l[j];
    }
    __syncthreads();

    if (bcnt <= BUCKET_CAP) {
        for (int i = bs + t; i < be; i += 256) {
            const uint2 r = rec[i];
            const int lpos = atomicAdd(&cur_l[(int)r.x - dlo], 1);
            slotbuf[lpos] = (int)r.y;
        }
        __syncthreads();
        for (int i = t; i < bcnt; i += 256)
            slot[bs + i] = slotbuf[i];
    } else {
        for (int i = bs + t; i < be; i += 256) {
            const uint2 r = rec[i];
            const int pos = bs + atomicAdd(&cur_l[(int)r.x - dlo], 1);
            slot[pos] = (int)r.y;
        }
    }
}

// ---------------------------------------------------------------------------
// v2e gather: one wave per hyperedge, lane = channel. fp16 payloads.
// ---------------------------------------------------------------------------
__global__ void gather_e_kernel(const int* __restrict__ slot, const int* __restrict__ off,
                                const int* __restrict__ deg, const __half* __restrict__ h,
                                __half* __restrict__ e_feat) {
    const int wid  = (blockIdx.x * blockDim.x + threadIdx.x) >> 6;
    const int lane = threadIdx.x & 63;
    if (wid >= N_HGE) return;
    const int n    = deg[wid];
    const int base = off[wid];
    float acc = 0.f;
    int j = 0;
    for (; j + 8 <= n; j += 8) {
        int v[8]; float r[8];
#pragma unroll
        for (int q = 0; q < 8; ++q) v[q] = slot[base + j + q];
#pragma unroll
        for (int q = 0; q < 8; ++q)
            r[q] = __half2float(h[(size_t)v[q] * C_OUT + lane]);
#pragma unroll
        for (int q = 0; q < 8; ++q) acc += r[q];
    }
    for (; j < n; ++j)
        acc += __half2float(h[(size_t)slot[base + j] * C_OUT + lane]);
    e_feat[(size_t)wid * C_OUT + lane] = __float2half_rn(acc / fmaxf((float)n, 1.f));
}

// ---------------------------------------------------------------------------
// Fused per-vertex epilogue. fp16 gather payloads, fp32 math + output.
// ---------------------------------------------------------------------------
__global__ void vertex_out_kernel(const int* __restrict__ slot_vhg,
                                  const int* __restrict__ off_vhg,
                                  const int* __restrict__ deg_vhg,
                                  const int* __restrict__ slot_vg,
                                  const int* __restrict__ off_vg,
                                  const int* __restrict__ deg_vg,
                                  const __half* __restrict__ e_feat,
                                  const __half* __restrict__ h,
                                  const float* __restrict__ w,
                                  float* __restrict__ out) {
    const int wid  = (blockIdx.x * blockDim.x + threadIdx.x) >> 6;
    const int lane = threadIdx.x & 63;
    if (wid >= N_VERTS) return;

    float acc_hg = 0.f;
    {
        const int n = deg_vhg[wid];
        const int base = off_vhg[wid];
        int j = 0;
        for (; j + 8 <= n; j += 8) {
            int e[8]; float r[8];
#pragma unroll
            for (int q = 0; q < 8; ++q) e[q] = slot_vhg[base + j + q];
#pragma unroll
            for (int q = 0; q < 8; ++q)
                r[q] = __half2float(e_feat[(size_t)e[q] * C_OUT + lane]);
#pragma unroll
            for (int q = 0; q < 8; ++q) acc_hg += r[q];
        }
        for (; j < n; ++j)
            acc_hg += __half2float(e_feat[(size_t)slot_vhg[base + j] * C_OUT + lane]);
        acc_hg /= fmaxf((float)n, 1.f);
    }

    float acc_g = 0.f;
    {
        const int n = deg_vg[wid];
        const int base = off_vg[wid];
        int j = 0;
        for (; j + 8 <= n; j += 8) {
            int v[8]; float r[8];
#pragma unroll
            for (int q = 0; q < 8; ++q) v[q] = slot_vg[base + j + q];
#pragma unroll
            for (int q = 0; q < 8; ++q)
                r[q] = __half2float(h[(size_t)v[q] * C_OUT + lane]);
#pragma unroll
            for (int q = 0; q < 8; ++q) acc_g += r[q];
        }
        for (; j < n; ++j)
            acc_g += __half2float(h[(size_t)slot_vg[base + j] * C_OUT + lane]);
        acc_g /= fmaxf((float)n, 1.f);
    }

    const float w0 = w[0], w1 = w[1];
    const float m  = fmaxf(w0, w1);
    const float e0 = __expf(w0 - m), e1 = __expf(w1 - m);
    const float sw0 = e0 / (e0 + e1), sw1 = e1 / (e0 + e1);

    const float hv = __half2float(h[(size_t)wid * C_OUT + lane]);
    float o = sw0 * 0.5f * (acc_g + acc_hg) + sw1 * hv;
    o = o > 0.f ? o : NEG * o;
    out[(size_t)wid * C_OUT + lane] = o;
}

// ---------------------------------------------------------------------------
extern "C" void kernel_launch(void* const* d_in, const int* in_sizes, int n_in,
                              void* d_out, int out_size, void* d_ws, size_t ws_size,
                              hipStream_t stream) {
    const float* x    = (const float*)d_in[0];
    const float* W1   = (const float*)d_in[1];
    const float* b1   = (const float*)d_in[2];
    const float* W2   = (const float*)d_in[3];
    const float* b2   = (const float*)d_in[4];
    const float* w    = (const float*)d_in[5];
    const int*  hg_v  = (const int*)d_in[6];
    const int*  hg_e  = (const int*)d_in[7];
    const int*  g_src = (const int*)d_in[8];
    const int*  g_dst = (const int*)d_in[9];
    float* out = (float*)d_out;

    // ---- workspace layout ----
    // Region R (reused): rec arrays during CSR build, then h/e_feat/Wsplit.
    uint2* rec_e   = (uint2*)d_ws;                 // N_INC   (12.8 MB)
    uint2* rec_vhg = rec_e   + N_INC;              // N_INC   (12.8 MB)
    uint2* rec_vg  = rec_vhg + N_INC;              // N_EDGES (12.8 MB)
    __half* h      = (__half*)d_ws;                // N_VERTS*64 fp16 (12.8 MB)
    __half* e_feat = h + (size_t)N_VERTS * C_OUT;  // N_HGE*64 fp16   (1.28 MB)
    ushort* W1t_h  = (ushort*)(e_feat + (size_t)N_HGE * C_OUT);  // 64 KB
    ushort* W1t_l  = W1t_h + C_IN * C_MID;                       // 64 KB
    ushort* W2t_h  = W1t_l + C_IN * C_MID;                       // 16 KB
    ushort* W2t_l  = W2t_h + C_MID * C_OUT;                      // 16 KB

    int* slot_e    = (int*)(rec_vg + N_EDGES);     // N_INC
    int* slot_vhg  = slot_e   + N_INC;             // N_INC
    int* slot_vg   = slot_vhg + N_INC;             // N_EDGES
    // zeroed int region:
    int* bktcnt_e   = slot_vg  + N_EDGES;          // NB_E
    int* bktcnt_vhg = bktcnt_e   + NB_E;           // NB_V
    int* bktcnt_vg  = bktcnt_vhg + NB_V;           // NB_V
    int* bcur_e     = bktcnt_vg  + NB_V;           // NB_E
    int* bcur_vhg   = bcur_e     + NB_E;           // NB_V
    int* bcur_vg    = bcur_vhg   + NB_V;           // NB_V
    // not zeroed:
    int* bstart_e   = bcur_vg    + NB_V;           // NB_E
    int* bstart_vhg = bstart_e   + NB_E;           // NB_V
    int* bstart_vg  = bstart_vhg + NB_V;           // NB_V
    int* deg_e      = bstart_vg  + NB_V;           // N_HGE
    int* deg_vhg    = deg_e      + N_HGE;          // N_VERTS
    int* deg_vg     = deg_vhg    + N_VERTS;        // N_VERTS
    int* off_e      = deg_vg     + N_VERTS;        // N_HGE
    int* off_vhg    = off_e      + N_HGE;          // N_VERTS
    int* off_vg     = off_vhg    + N_VERTS;        // N_VERTS

    const size_t zero_elems = 2 * ((size_t)NB_E + 2 * (size_t)NB_V);
    hipMemsetAsync(bktcnt_e, 0, zero_elems * sizeof(int), stream);

    // ---- CSR build ----
    const int partA_blocks = (N_INC + PAIRS_PER_BLOCK - 1) / PAIRS_PER_BLOCK;
    bucket_count_kernel<<<partA_blocks, 256, 0, stream>>>(
        hg_e, hg_v, g_dst, bktcnt_e, bktcnt_vhg, bktcnt_vg);
    bucket_scan_kernel<<<3, 256, 0, stream>>>(bktcnt_e, bstart_e,
                                              bktcnt_vhg, bstart_vhg,
                                              bktcnt_vg, bstart_vg);
    partitionA_kernel<<<partA_blocks, 256, 0, stream>>>(
        hg_v, hg_e, g_src, g_dst, bstart_e, bstart_vhg, bstart_vg,
        bcur_e, bcur_vhg, bcur_vg, rec_e, rec_vhg, rec_vg);
    partitionB_kernel<<<GRID_B, 256, 0, stream>>>(
        rec_e, rec_vhg, rec_vg, bstart_e, bstart_vhg, bstart_vg,
        deg_e, deg_vhg, deg_vg, off_e, off_vhg, off_vg,
        slot_e, slot_vhg, slot_vg);

    // ---- weight split (after B: rec region dead) ----
    prep_w_kernel<<<(C_IN * C_MID + C_MID * C_OUT + 255) / 256, 256, 0, stream>>>(
        W1, W2, W1t_h, W1t_l, W2t_h, W2t_l);

    // ---- MFMA MLP (h aliases rec region, fp16 out) ----
    mlp_mfma_kernel<<<(N_VERTS + MBM - 1) / MBM, 256, 0, stream>>>(
        x, W1t_h, W1t_l, W2t_h, W2t_l, b1, b2, h);

    // ---- v2e gather ----
    const int ge_blocks = (int)(((size_t)N_HGE * 64 + 255) / 256);
    gather_e_kernel<<<ge_blocks, 256, 0, stream>>>(slot_e, off_e, deg_e, h, e_feat);

    // ---- fused e2v + graph gather + finalize ----
    const int vo_blocks = (int)(((size_t)N_VERTS * 64 + 255) / 256);
    vertex_out_kernel<<<vo_blocks, 256, 0, stream>>>(slot_vhg, off_vhg, deg_vhg,
                                                     slot_vg, off_vg, deg_vg,
                                                     e_feat, h, w, out);
}

// Round 4
// 478.344 us; speedup vs baseline: 2.0257x; 1.0862x over previous
//
#include <hip/hip_runtime.h>
#include <hip/hip_bf16.h>
#include <hip/hip_fp16.h>

// Problem constants (fixed by the reference setup)
#define N_VERTS   100000
#define N_HGE     10000
#define N_INC     1600000
#define N_EDGES   1600000
#define C_IN      256
#define C_MID     128
#define C_OUT     64
#define NEG       0.2f

// Radix-partition parameters.
#define EBSHIFT 6
#define NB_E    157              // ceil(10000/64)
#define VBSHIFT 9
#define NB_V    196              // ceil(100000/512)
#define NB_MAX  196
#define PAIRS_PER_BLOCK 4096     // 256 threads x 16
#define QP 16
#define BUCKET_CAP 16384

typedef __attribute__((ext_vector_type(8))) short  bf16x8;
typedef __attribute__((ext_vector_type(4))) float  f32x4;

// Truncation split: v = hi + lo with |err| <~ 2^-16 |v|.
__device__ __forceinline__ void split1(float v, ushort& hi, ushort& lo) {
    const unsigned b = __float_as_uint(v);
    hi = (ushort)(b >> 16);
    const float r = v - __uint_as_float(b & 0xffff0000u);
    lo = (ushort)(__float_as_uint(r) >> 16);
}

// Unpack 4 fp16 (as uint2) and accumulate into float4.
__device__ __forceinline__ void h4acc(float4& a, uint2 p) {
    const __half2 h01 = *(__half2*)&p.x;
    const __half2 h23 = *(__half2*)&p.y;
    const float2 f01 = __half22float2(h01);
    const float2 f23 = __half22float2(h23);
    a.x += f01.x; a.y += f01.y; a.z += f23.x; a.w += f23.y;
}

// Sum float4 across the 4 sub-groups (lanes l, l^16, l^32, l^48).
__device__ __forceinline__ float4 xreduce4(float4 a) {
#pragma unroll
    for (int m = 16; m <= 32; m <<= 1) {
        a.x += __shfl_xor(a.x, m);
        a.y += __shfl_xor(a.y, m);
        a.z += __shfl_xor(a.z, m);
        a.w += __shfl_xor(a.w, m);
    }
    return a;
}

// ---------------------------------------------------------------------------
// One-time weight prep: split W1/W2 into (hi,lo) bf16 and TRANSPOSE to [n][k].
// ---------------------------------------------------------------------------
__global__ __launch_bounds__(256) void
prep_w_kernel(const float* __restrict__ W1, const float* __restrict__ W2,
              ushort* __restrict__ W1t_h, ushort* __restrict__ W1t_l,
              ushort* __restrict__ W2t_h, ushort* __restrict__ W2t_l) {
    const int idx = blockIdx.x * 256 + threadIdx.x;
    if (idx < C_IN * C_MID) {                       // W1t[n][k], n<128,k<256
        const int n = idx >> 8, k = idx & 255;
        ushort hi, lo;
        split1(W1[k * C_MID + n], hi, lo);
        W1t_h[idx] = hi; W1t_l[idx] = lo;
    } else {
        const int j = idx - C_IN * C_MID;
        if (j < C_MID * C_OUT) {                    // W2t[n][k], n<64,k<128
            const int n = j >> 7, k = j & 127;
            ushort hi, lo;
            split1(W2[k * C_OUT + n], hi, lo);
            W2t_h[j] = hi; W2t_l[j] = lo;
        }
    }
}

// ---------------------------------------------------------------------------
// MFMA MLP: h = leaky_relu(x @ W1 + b1) @ W2 + b2, split-bf16 (3-term).
// Output h stored as fp16 (gather payload downstream; 2^-11 rel error).
// ---------------------------------------------------------------------------
#define MBM 128
__global__ __launch_bounds__(256) void
mlp_mfma_kernel(const float* __restrict__ x,
                const ushort* __restrict__ W1t_h, const ushort* __restrict__ W1t_l,
                const ushort* __restrict__ W2t_h, const ushort* __restrict__ W2t_l,
                const float* __restrict__ b1, const float* __restrict__ b2,
                __half* __restrict__ h) {
    // union LDS: phase1 = xs_h/xs_l/ws_h/ws_l [128][72]; phase2 = mid_h/mid_l [128][136]
    __shared__ ushort buf[36864];                  // 72 KB
    ushort* xs_h = buf;                            // [128][72]
    ushort* xs_l = buf + 9216;
    ushort* ws_h = buf + 18432;                    // [128][72]
    ushort* ws_l = buf + 27648;
    ushort* mid_h = buf;                           // [128][136]
    ushort* mid_l = buf + 17408;

    const int t    = threadIdx.x;
    const int lane = t & 63;
    const int wid  = t >> 6;
    const int wr   = wid >> 1, wc = wid & 1;       // 2x2 wave grid
    const int v0   = blockIdx.x * MBM;
    const int rem  = N_VERTS - v0;                 // <128 only in last block
    const int l15  = lane & 15;
    const int lg   = lane >> 4;                    // 0..3

    f32x4 acc[4][4];
#pragma unroll
    for (int i = 0; i < 4; ++i)
#pragma unroll
        for (int j = 0; j < 4; ++j) acc[i][j] = (f32x4)0.f;

    // ---- layer 1: K tiled by 64 (4 tiles), split-bf16 staged in LDS ----
    for (int kt = 0; kt < 4; ++kt) {
        __syncthreads();
#pragma unroll
        for (int it = 0; it < 8; ++it) {           // x tile: 2048 float4
            const int idx = it * 256 + t;
            const int row = idx >> 4;
            const int c4  = (idx & 15) * 4;
            float4 v = make_float4(0.f, 0.f, 0.f, 0.f);
            if (row < rem)
                v = *(const float4*)&x[(size_t)(v0 + row) * C_IN + kt * 64 + c4];
            ushort h0,h1,h2,h3, l0,l1,l2,l3;
            split1(v.x, h0, l0); split1(v.y, h1, l1);
            split1(v.z, h2, l2); split1(v.w, h3, l3);
            uint2 ph, pl;
            ph.x = (unsigned)h0 | ((unsigned)h1 << 16);
            ph.y = (unsigned)h2 | ((unsigned)h3 << 16);
            pl.x = (unsigned)l0 | ((unsigned)l1 << 16);
            pl.y = (unsigned)l2 | ((unsigned)l3 << 16);
            *(uint2*)&xs_h[row * 72 + c4] = ph;
            *(uint2*)&xs_l[row * 72 + c4] = pl;
        }
#pragma unroll
        for (int it = 0; it < 8; ++it) {           // W1t tile
            const int idx = it * 256 + t;
            const int n  = idx >> 4;
            const int c4 = (idx & 15) * 4;
            *(uint2*)&ws_h[n * 72 + c4] = *(const uint2*)&W1t_h[n * 256 + kt * 64 + c4];
            *(uint2*)&ws_l[n * 72 + c4] = *(const uint2*)&W1t_l[n * 256 + kt * 64 + c4];
        }
        __syncthreads();

#pragma unroll
        for (int ks = 0; ks < 2; ++ks) {
            const int k0 = ks * 32 + lg * 8;
            bf16x8 ah[4], al[4], bh[4], bl[4];
#pragma unroll
            for (int mf = 0; mf < 4; ++mf) {
                const int r = wr * 64 + mf * 16 + l15;
                ah[mf] = *(const bf16x8*)&xs_h[r * 72 + k0];
                al[mf] = *(const bf16x8*)&xs_l[r * 72 + k0];
            }
#pragma unroll
            for (int nf = 0; nf < 4; ++nf) {
                const int n = wc * 64 + nf * 16 + l15;
                bh[nf] = *(const bf16x8*)&ws_h[n * 72 + k0];
                bl[nf] = *(const bf16x8*)&ws_l[n * 72 + k0];
            }
#pragma unroll
            for (int mf = 0; mf < 4; ++mf)
#pragma unroll
                for (int nf = 0; nf < 4; ++nf) {
                    acc[mf][nf] = __builtin_amdgcn_mfma_f32_16x16x32_bf16(
                        ah[mf], bh[nf], acc[mf][nf], 0, 0, 0);
                    acc[mf][nf] = __builtin_amdgcn_mfma_f32_16x16x32_bf16(
                        al[mf], bh[nf], acc[mf][nf], 0, 0, 0);
                    acc[mf][nf] = __builtin_amdgcn_mfma_f32_16x16x32_bf16(
                        ah[mf], bl[nf], acc[mf][nf], 0, 0, 0);
                }
        }
    }
    __syncthreads();

    // ---- bias + leaky, split-write mid[m][k] ----
#pragma unroll
    for (int nf = 0; nf < 4; ++nf) {
        const int col = wc * 64 + nf * 16 + l15;
        const float bias = b1[col];
#pragma unroll
        for (int mf = 0; mf < 4; ++mf)
#pragma unroll
            for (int j = 0; j < 4; ++j) {
                const int r = wr * 64 + mf * 16 + lg * 4 + j;
                float v = acc[mf][nf][j] + bias;
                v = v > 0.f ? v : NEG * v;
                ushort hi, lo;
                split1(v, hi, lo);
                mid_h[r * 136 + col] = hi;
                mid_l[r * 136 + col] = lo;
            }
    }
    __syncthreads();

    // ---- layer 2: K = 128 ----
    f32x4 acc2[4][2];
#pragma unroll
    for (int i = 0; i < 4; ++i) { acc2[i][0] = (f32x4)0.f; acc2[i][1] = (f32x4)0.f; }

#pragma unroll
    for (int ks = 0; ks < 4; ++ks) {
        const int k0 = ks * 32 + lg * 8;
        bf16x8 ah[4], al[4];
#pragma unroll
        for (int mf = 0; mf < 4; ++mf) {
            const int r = wr * 64 + mf * 16 + l15;
            ah[mf] = *(const bf16x8*)&mid_h[r * 136 + k0];
            al[mf] = *(const bf16x8*)&mid_l[r * 136 + k0];
        }
#pragma unroll
        for (int nf = 0; nf < 2; ++nf) {
            const int n = wc * 32 + nf * 16 + l15;
            const bf16x8 bh = *(const bf16x8*)&W2t_h[n * 128 + k0];
            const bf16x8 bl = *(const bf16x8*)&W2t_l[n * 128 + k0];
#pragma unroll
            for (int mf = 0; mf < 4; ++mf) {
                acc2[mf][nf] = __builtin_amdgcn_mfma_f32_16x16x32_bf16(
                    ah[mf], bh, acc2[mf][nf], 0, 0, 0);
                acc2[mf][nf] = __builtin_amdgcn_mfma_f32_16x16x32_bf16(
                    al[mf], bh, acc2[mf][nf], 0, 0, 0);
                acc2[mf][nf] = __builtin_amdgcn_mfma_f32_16x16x32_bf16(
                    ah[mf], bl, acc2[mf][nf], 0, 0, 0);
            }
        }
    }

    // ---- store h as fp16 ----
#pragma unroll
    for (int nf = 0; nf < 2; ++nf) {
        const int col = wc * 32 + nf * 16 + l15;
        const float bias = b2[col];
#pragma unroll
        for (int mf = 0; mf < 4; ++mf)
#pragma unroll
            for (int j = 0; j < 4; ++j) {
                const int r = wr * 64 + mf * 16 + lg * 4 + j;
                if (r < rem)
                    h[(size_t)(v0 + r) * C_OUT + col] =
                        __float2half_rn(acc2[mf][nf][j] + bias);
            }
    }
}

// ---------------------------------------------------------------------------
// Bucket-granularity count.
// ---------------------------------------------------------------------------
__global__ __launch_bounds__(256) void
bucket_count_kernel(const int* __restrict__ hg_e, const int* __restrict__ hg_v,
                    const int* __restrict__ g_dst,
                    int* __restrict__ bktcnt_e, int* __restrict__ bktcnt_vhg,
                    int* __restrict__ bktcnt_vg) {
    __shared__ int hist[NB_MAX];
    const int t  = threadIdx.x;
    const int i0 = blockIdx.x * PAIRS_PER_BLOCK + t;

    for (int table = 0; table < 3; ++table) {
        const int* dsts; int* bktcnt; int shift, nb;
        if (table == 0)      { dsts = hg_e;  bktcnt = bktcnt_e;   shift = EBSHIFT; nb = NB_E; }
        else if (table == 1) { dsts = hg_v;  bktcnt = bktcnt_vhg; shift = VBSHIFT; nb = NB_V; }
        else                 { dsts = g_dst; bktcnt = bktcnt_vg;  shift = VBSHIFT; nb = NB_V; }

        if (t < nb) hist[t] = 0;
        __syncthreads();
#pragma unroll
        for (int q = 0; q < QP; ++q) {
            const int i = i0 + q * 256;
            if (i < N_INC) atomicAdd(&hist[dsts[i] >> shift], 1);
        }
        __syncthreads();
        if (t < nb) {
            const int c = hist[t];
            if (c) atomicAdd(&bktcnt[t], c);
        }
        __syncthreads();
    }
}

// Three tiny exclusive scans over bucket counts (<=196 each) in one dispatch.
__global__ __launch_bounds__(256) void
bucket_scan_kernel(const int* __restrict__ bktcnt_e,   int* __restrict__ bstart_e,
                   const int* __restrict__ bktcnt_vhg, int* __restrict__ bstart_vhg,
                   const int* __restrict__ bktcnt_vg,  int* __restrict__ bstart_vg) {
    __shared__ int s[256];
    const int* cnt; int* bs; int nb;
    if (blockIdx.x == 0)      { cnt = bktcnt_e;   bs = bstart_e;   nb = NB_E; }
    else if (blockIdx.x == 1) { cnt = bktcnt_vhg; bs = bstart_vhg; nb = NB_V; }
    else                      { cnt = bktcnt_vg;  bs = bstart_vg;  nb = NB_V; }
    const int t = threadIdx.x;
    const int own = (t < nb) ? cnt[t] : 0;
    s[t] = own;
    __syncthreads();
    for (int d = 1; d < 256; d <<= 1) {
        int v = (t >= d) ? s[t - d] : 0;
        __syncthreads();
        s[t] += v;
        __syncthreads();
    }
    if (t < nb) bs[t] = s[t] - own;   // exclusive
}

// ---------------------------------------------------------------------------
// Phase A: radix partition into bucket-dense record runs.
// ---------------------------------------------------------------------------
__global__ __launch_bounds__(256) void
partitionA_kernel(const int* __restrict__ hg_v, const int* __restrict__ hg_e,
                  const int* __restrict__ g_src, const int* __restrict__ g_dst,
                  const int* __restrict__ bstart_e, const int* __restrict__ bstart_vhg,
                  const int* __restrict__ bstart_vg,
                  int* __restrict__ bcur_e, int* __restrict__ bcur_vhg,
                  int* __restrict__ bcur_vg,
                  uint2* __restrict__ rec_e, uint2* __restrict__ rec_vhg,
                  uint2* __restrict__ rec_vg) {
    __shared__ int hist[NB_MAX];
    __shared__ int gb[NB_MAX];
    __shared__ int bb[NB_MAX];
    const int t  = threadIdx.x;
    const int i0 = blockIdx.x * PAIRS_PER_BLOCK + t;

    for (int table = 0; table < 3; ++table) {
        const int *dsts, *pays, *bstart;
        int *bcur; uint2* rec;
        int shift, nb;
        if (table == 0)      { dsts = hg_e;  pays = hg_v;  bstart = bstart_e;
                               bcur = bcur_e;   rec = rec_e;   shift = EBSHIFT; nb = NB_E; }
        else if (table == 1) { dsts = hg_v;  pays = hg_e;  bstart = bstart_vhg;
                               bcur = bcur_vhg; rec = rec_vhg; shift = VBSHIFT; nb = NB_V; }
        else                 { dsts = g_dst; pays = g_src; bstart = bstart_vg;
                               bcur = bcur_vg;  rec = rec_vg;  shift = VBSHIFT; nb = NB_V; }

        if (t < nb) hist[t] = 0;
        __syncthreads();

        int d[QP], p[QP], bk[QP], rk[QP];
#pragma unroll
        for (int q = 0; q < QP; ++q) {
            const int i = i0 + q * 256;
            if (i < N_INC) {
                d[q]  = dsts[i];
                p[q]  = pays[i];
                bk[q] = d[q] >> shift;
                rk[q] = atomicAdd(&hist[bk[q]], 1);
            } else bk[q] = -1;
        }
        __syncthreads();

        if (t < nb) {
            gb[t] = atomicAdd(&bcur[t], hist[t]);
            bb[t] = bstart[t];
        }
        __syncthreads();

#pragma unroll
        for (int q = 0; q < QP; ++q) {
            if (bk[q] >= 0) {
                const int pos = bb[bk[q]] + gb[bk[q]] + rk[q];
                rec[pos] = make_uint2((unsigned)d[q], (unsigned)p[q]);
            }
        }
        __syncthreads();
    }
}

// ---------------------------------------------------------------------------
// Phase B: per-bucket CSR derivation + dense slot build in LDS.
// ---------------------------------------------------------------------------
#define GRID_B (NB_E + 2 * NB_V)
__global__ __launch_bounds__(256) void
partitionB_kernel(const uint2* __restrict__ rec_e, const uint2* __restrict__ rec_vhg,
                  const uint2* __restrict__ rec_vg,
                  const int* __restrict__ bstart_e, const int* __restrict__ bstart_vhg,
                  const int* __restrict__ bstart_vg,
                  int* __restrict__ deg_e, int* __restrict__ deg_vhg,
                  int* __restrict__ deg_vg,
                  int* __restrict__ off_e, int* __restrict__ off_vhg,
                  int* __restrict__ off_vg,
                  int* __restrict__ slot_e, int* __restrict__ slot_vhg,
                  int* __restrict__ slot_vg) {
    __shared__ int slotbuf[BUCKET_CAP];   // 64 KB
    __shared__ int cnt_l[1 << VBSHIFT];   // 2 KB
    __shared__ int cur_l[1 << VBSHIFT];   // 2 KB
    __shared__ int part[256];             // 1 KB

    int blk = blockIdx.x;
    const uint2* rec; const int* bstart; int* deg; int* off; int* slot;
    int b, shift, ndst, nb;
    if (blk < NB_E) {
        rec = rec_e; bstart = bstart_e; deg = deg_e; off = off_e; slot = slot_e;
        shift = EBSHIFT; ndst = N_HGE; nb = NB_E; b = blk;
    } else if (blk < NB_E + NB_V) {
        rec = rec_vhg; bstart = bstart_vhg; deg = deg_vhg; off = off_vhg; slot = slot_vhg;
        shift = VBSHIFT; ndst = N_VERTS; nb = NB_V; b = blk - NB_E;
    } else {
        rec = rec_vg; bstart = bstart_vg; deg = deg_vg; off = off_vg; slot = slot_vg;
        shift = VBSHIFT; ndst = N_VERTS; nb = NB_V; b = blk - NB_E - NB_V;
    }
    const int t    = threadIdx.x;
    const int dlo  = b << shift;
    const int nd   = 1 << shift;
    const int ndc  = min(nd, ndst - dlo);
    const int bs   = bstart[b];
    const int be   = (b == nb - 1) ? N_INC : bstart[b + 1];
    const int bcnt = be - bs;

    for (int j = t; j < nd; j += 256) cnt_l[j] = 0;
    __syncthreads();
    for (int i = bs + t; i < be; i += 256)
        atomicAdd(&cnt_l[(int)rec[i].x - dlo], 1);
    __syncthreads();

    const int chunk = (nd + 255) / 256;     // 1 or 2
    const int lo = t * chunk;
    const int hi = min(lo + chunk, nd);
    int s = 0;
    for (int j = lo; j < hi; ++j) s += cnt_l[j];
    part[t] = s;
    __syncthreads();
    for (int d = 1; d < 256; d <<= 1) {
        int v = (t >= d) ? part[t - d] : 0;
        __syncthreads();
        part[t] += v;
        __syncthreads();
    }
    int run = (t > 0) ? part[t - 1] : 0;
    for (int j = lo; j < hi; ++j) { cur_l[j] = run; run += cnt_l[j]; }
    __syncthreads();

    for (int j = t; j < ndc; j += 256) {
        deg[dlo + j] = cnt_l[j];
        off[dlo + j] = bs + cur_l[j];
    }
    __syncthreads();

    if (bcnt <= BUCKET_CAP) {
        for (int i = bs + t; i < be; i += 256) {
            const uint2 r = rec[i];
            const int lpos = atomicAdd(&cur_l[(int)r.x - dlo], 1);
            slotbuf[lpos] = (int)r.y;
        }
        __syncthreads();
        for (int i = t; i < bcnt; i += 256)
            slot[bs + i] = slotbuf[i];
    } else {
        for (int i = bs + t; i < be; i += 256) {
            const uint2 r = rec[i];
            const int pos = bs + atomicAdd(&cur_l[(int)r.x - dlo], 1);
            slot[pos] = (int)r.y;
        }
    }
}

// ---------------------------------------------------------------------------
// v2e gather: one wave per hyperedge, quad-slot (4 slots/instr, 16 lanes/row,
// 8B half4 loads). sub = lane>>4 picks slot, cp = lane&15 picks channel quad.
// ---------------------------------------------------------------------------
__global__ void gather_e_kernel(const int* __restrict__ slot, const int* __restrict__ off,
                                const int* __restrict__ deg, const __half* __restrict__ h,
                                __half* __restrict__ e_feat) {
    const int wid  = (blockIdx.x * blockDim.x + threadIdx.x) >> 6;
    const int lane = threadIdx.x & 63;
    if (wid >= N_HGE) return;
    const int sub = lane >> 4;
    const int cp  = lane & 15;
    const int n    = deg[wid];
    const int base = off[wid];

    float4 acc = make_float4(0.f, 0.f, 0.f, 0.f);
    int j = 0;
    for (; j + 16 <= n; j += 16) {
#pragma unroll
        for (int q = 0; q < 4; ++q) {
            const int s = slot[base + j + 4 * q + sub];
            h4acc(acc, *(const uint2*)&h[(size_t)s * C_OUT + 4 * cp]);
        }
    }
    for (; j < n; j += 4) {                      // guarded quad tail
        const int idx = j + sub;
        const int s = slot[base + (idx < n ? idx : 0)];
        const uint2 p = *(const uint2*)&h[(size_t)s * C_OUT + 4 * cp];
        if (idx < n) h4acc(acc, p);
    }
    acc = xreduce4(acc);
    const float inv = 1.f / fmaxf((float)n, 1.f);
    if (sub == 0) {
        const __half2 r01 = __float22half2_rn(make_float2(acc.x * inv, acc.y * inv));
        const __half2 r23 = __float22half2_rn(make_float2(acc.z * inv, acc.w * inv));
        uint2 pk;
        pk.x = *(const unsigned*)&r01;
        pk.y = *(const unsigned*)&r23;
        *(uint2*)&e_feat[(size_t)wid * C_OUT + 4 * cp] = pk;
    }
}

// ---------------------------------------------------------------------------
// Fused per-vertex epilogue, quad-slot gathers over e_feat and h.
// ---------------------------------------------------------------------------
__global__ void vertex_out_kernel(const int* __restrict__ slot_vhg,
                                  const int* __restrict__ off_vhg,
                                  const int* __restrict__ deg_vhg,
                                  const int* __restrict__ slot_vg,
                                  const int* __restrict__ off_vg,
                                  const int* __restrict__ deg_vg,
                                  const __half* __restrict__ e_feat,
                                  const __half* __restrict__ h,
                                  const float* __restrict__ w,
                                  float* __restrict__ out) {
    const int wid  = (blockIdx.x * blockDim.x + threadIdx.x) >> 6;
    const int lane = threadIdx.x & 63;
    if (wid >= N_VERTS) return;
    const int sub = lane >> 4;
    const int cp  = lane & 15;

    float4 a_hg = make_float4(0.f, 0.f, 0.f, 0.f);
    float inv_hg;
    {
        const int n = deg_vhg[wid];
        const int base = off_vhg[wid];
        int j = 0;
        for (; j + 16 <= n; j += 16) {
#pragma unroll
            for (int q = 0; q < 4; ++q) {
                const int s = slot_vhg[base + j + 4 * q + sub];
                h4acc(a_hg, *(const uint2*)&e_feat[(size_t)s * C_OUT + 4 * cp]);
            }
        }
        for (; j < n; j += 4) {
            const int idx = j + sub;
            const int s = slot_vhg[base + (idx < n ? idx : 0)];
            const uint2 p = *(const uint2*)&e_feat[(size_t)s * C_OUT + 4 * cp];
            if (idx < n) h4acc(a_hg, p);
        }
        inv_hg = 1.f / fmaxf((float)n, 1.f);
    }

    float4 a_g = make_float4(0.f, 0.f, 0.f, 0.f);
    float inv_g;
    {
        const int n = deg_vg[wid];
        const int base = off_vg[wid];
        int j = 0;
        for (; j + 16 <= n; j += 16) {
#pragma unroll
            for (int q = 0; q < 4; ++q) {
                const int s = slot_vg[base + j + 4 * q + sub];
                h4acc(a_g, *(const uint2*)&h[(size_t)s * C_OUT + 4 * cp]);
            }
        }
        for (; j < n; j += 4) {
            const int idx = j + sub;
            const int s = slot_vg[base + (idx < n ? idx : 0)];
            const uint2 p = *(const uint2*)&h[(size_t)s * C_OUT + 4 * cp];
            if (idx < n) h4acc(a_g, p);
        }
        inv_g = 1.f / fmaxf((float)n, 1.f);
    }

    a_hg = xreduce4(a_hg);
    a_g  = xreduce4(a_g);

    const float w0 = w[0], w1 = w[1];
    const float m  = fmaxf(w0, w1);
    const float e0 = __expf(w0 - m), e1 = __expf(w1 - m);
    const float sw0 = e0 / (e0 + e1), sw1 = e1 / (e0 + e1);
    const float c0 = sw0 * 0.5f;

    float4 hv = make_float4(0.f, 0.f, 0.f, 0.f);
    h4acc(hv, *(const uint2*)&h[(size_t)wid * C_OUT + 4 * cp]);

    float4 o;
    o.x = c0 * (a_g.x * inv_g + a_hg.x * inv_hg) + sw1 * hv.x;
    o.y = c0 * (a_g.y * inv_g + a_hg.y * inv_hg) + sw1 * hv.y;
    o.z = c0 * (a_g.z * inv_g + a_hg.z * inv_hg) + sw1 * hv.z;
    o.w = c0 * (a_g.w * inv_g + a_hg.w * inv_hg) + sw1 * hv.w;
    o.x = o.x > 0.f ? o.x : NEG * o.x;
    o.y = o.y > 0.f ? o.y : NEG * o.y;
    o.z = o.z > 0.f ? o.z : NEG * o.z;
    o.w = o.w > 0.f ? o.w : NEG * o.w;

    if (sub == 0)
        *(float4*)&out[(size_t)wid * C_OUT + 4 * cp] = o;
}

// ---------------------------------------------------------------------------
extern "C" void kernel_launch(void* const* d_in, const int* in_sizes, int n_in,
                              void* d_out, int out_size, void* d_ws, size_t ws_size,
                              hipStream_t stream) {
    const float* x    = (const float*)d_in[0];
    const float* W1   = (const float*)d_in[1];
    const float* b1   = (const float*)d_in[2];
    const float* W2   = (const float*)d_in[3];
    const float* b2   = (const float*)d_in[4];
    const float* w    = (const float*)d_in[5];
    const int*  hg_v  = (const int*)d_in[6];
    const int*  hg_e  = (const int*)d_in[7];
    const int*  g_src = (const int*)d_in[8];
    const int*  g_dst = (const int*)d_in[9];
    float* out = (float*)d_out;

    // ---- workspace layout ----
    // Region R (reused): rec arrays during CSR build, then h/e_feat/Wsplit.
    uint2* rec_e   = (uint2*)d_ws;                 // N_INC   (12.8 MB)
    uint2* rec_vhg = rec_e   + N_INC;              // N_INC   (12.8 MB)
    uint2* rec_vg  = rec_vhg + N_INC;              // N_EDGES (12.8 MB)
    __half* h      = (__half*)d_ws;                // N_VERTS*64 fp16 (12.8 MB)
    __half* e_feat = h + (size_t)N_VERTS * C_OUT;  // N_HGE*64 fp16   (1.28 MB)
    ushort* W1t_h  = (ushort*)(e_feat + (size_t)N_HGE * C_OUT);  // 64 KB
    ushort* W1t_l  = W1t_h + C_IN * C_MID;                       // 64 KB
    ushort* W2t_h  = W1t_l + C_IN * C_MID;                       // 16 KB
    ushort* W2t_l  = W2t_h + C_MID * C_OUT;                      // 16 KB

    int* slot_e    = (int*)(rec_vg + N_EDGES);     // N_INC
    int* slot_vhg  = slot_e   + N_INC;             // N_INC
    int* slot_vg   = slot_vhg + N_INC;             // N_EDGES
    // zeroed int region:
    int* bktcnt_e   = slot_vg  + N_EDGES;          // NB_E
    int* bktcnt_vhg = bktcnt_e   + NB_E;           // NB_V
    int* bktcnt_vg  = bktcnt_vhg + NB_V;           // NB_V
    int* bcur_e     = bktcnt_vg  + NB_V;           // NB_E
    int* bcur_vhg   = bcur_e     + NB_E;           // NB_V
    int* bcur_vg    = bcur_vhg   + NB_V;           // NB_V
    // not zeroed:
    int* bstart_e   = bcur_vg    + NB_V;           // NB_E
    int* bstart_vhg = bstart_e   + NB_E;           // NB_V
    int* bstart_vg  = bstart_vhg + NB_V;           // NB_V
    int* deg_e      = bstart_vg  + NB_V;           // N_HGE
    int* deg_vhg    = deg_e      + N_HGE;          // N_VERTS
    int* deg_vg     = deg_vhg    + N_VERTS;        // N_VERTS
    int* off_e      = deg_vg     + N_VERTS;        // N_HGE
    int* off_vhg    = off_e      + N_HGE;          // N_VERTS
    int* off_vg     = off_vhg    + N_VERTS;        // N_VERTS

    const size_t zero_elems = 2 * ((size_t)NB_E + 2 * (size_t)NB_V);
    hipMemsetAsync(bktcnt_e, 0, zero_elems * sizeof(int), stream);

    // ---- CSR build ----
    const int partA_blocks = (N_INC + PAIRS_PER_BLOCK - 1) / PAIRS_PER_BLOCK;
    bucket_count_kernel<<<partA_blocks, 256, 0, stream>>>(
        hg_e, hg_v, g_dst, bktcnt_e, bktcnt_vhg, bktcnt_vg);
    bucket_scan_kernel<<<3, 256, 0, stream>>>(bktcnt_e, bstart_e,
                                              bktcnt_vhg, bstart_vhg,
                                              bktcnt_vg, bstart_vg);
    partitionA_kernel<<<partA_blocks, 256, 0, stream>>>(
        hg_v, hg_e, g_src, g_dst, bstart_e, bstart_vhg, bstart_vg,
        bcur_e, bcur_vhg, bcur_vg, rec_e, rec_vhg, rec_vg);
    partitionB_kernel<<<GRID_B, 256, 0, stream>>>(
        rec_e, rec_vhg, rec_vg, bstart_e, bstart_vhg, bstart_vg,
        deg_e, deg_vhg, deg_vg, off_e, off_vhg, off_vg,
        slot_e, slot_vhg, slot_vg);

    // ---- weight split (after B: rec region dead) ----
    prep_w_kernel<<<(C_IN * C_MID + C_MID * C_OUT + 255) / 256, 256, 0, stream>>>(
        W1, W2, W1t_h, W1t_l, W2t_h, W2t_l);

    // ---- MFMA MLP (h aliases rec region, fp16 out) ----
    mlp_mfma_kernel<<<(N_VERTS + MBM - 1) / MBM, 256, 0, stream>>>(
        x, W1t_h, W1t_l, W2t_h, W2t_l, b1, b2, h);

    // ---- v2e gather ----
    const int ge_blocks = (int)(((size_t)N_HGE * 64 + 255) / 256);
    gather_e_kernel<<<ge_blocks, 256, 0, stream>>>(slot_e, off_e, deg_e, h, e_feat);

    // ---- fused e2v + graph gather + finalize ----
    const int vo_blocks = (int)(((size_t)N_VERTS * 64 + 255) / 256);
    vertex_out_kernel<<<vo_blocks, 256, 0, stream>>>(slot_vhg, off_vhg, deg_vhg,
                                                     slot_vg, off_vg, deg_vg,
                                                     e_feat, h, w, out);
}